// Round 2
// baseline (233.073 us; speedup 1.0000x reference)
//
#include <hip/hip_runtime.h>
#include <hip/hip_bf16.h>
#include <cmath>

// Problem constants (fixed by the reference)
constexpr int CB  = 8;     // batch
constexpr int CN  = 1024;  // sequence length
constexpr int CD  = 256;   // model dim
constexpr int CH  = 8;     // heads
constexpr int CDH = 32;    // head dim
constexpr int CR  = 4;     // relation types (adj value 4 = none)
constexpr int CFF = 1024;  // ffn dim
constexpr float CEPS = 1e-5f;
constexpr float CS = 0.25503480f;   // (1/sqrt(32)) * log2(e), folded into Q
constexpr size_t SZH = (size_t)CB * CH * CN * CDH;  // 2M: one head-plane

#define MODE_QK    0   // scatter bf16 q/k head-major planes, +bias (cols 0..511)
#define MODE_FFN1  2   // +bias, tanh-gelu -> bf16
#define MODE_VT    4   // V^T gemm (A=weight rows, B=src rows): c-order column store

typedef float v4f __attribute__((ext_vector_type(4)));
typedef short v8s __attribute__((ext_vector_type(8)));

static __device__ __forceinline__ short f2bf(float f) {
    unsigned u = __builtin_bit_cast(unsigned, f);
    u += 0x7fff + ((u >> 16) & 1);          // round-to-nearest-even
    return (short)(u >> 16);
}
static __device__ __forceinline__ float bf2f(short s) {
    unsigned u = ((unsigned)(unsigned short)s) << 16;
    return __builtin_bit_cast(float, u);
}
static __device__ __forceinline__ unsigned cvtpk_bf16(float lo, float hi) {
    unsigned r;
    asm("v_cvt_pk_bf16_f32 %0, %1, %2" : "=v"(r) : "v"(lo), "v"(hi));
    return r;
}

static __device__ __forceinline__ void async_copy16(const void* g, void* l) {
    __builtin_amdgcn_global_load_lds(
        (const __attribute__((address_space(1))) void*)g,
        (__attribute__((address_space(3))) void*)l, 16, 0, 0);
}

// LDS bank-conflict swizzle for 64B-row tiles staged by global_load_lds:
// linear LDS dest + XOR-permuted global SOURCE granule; fragment reads
// un-swizzle with quad ^ ((row>>1)&3).  Makes every 8-lane issue group hit
// 8 distinct 4-bank granules (was 4-way conflict at stride 64B).

// ---------------------------------------------------------------------------
// bf16 MFMA GEMM body (device fn, dynamic LDS): epilogue(A[M,K] @ Bw[N,K])
// BM x BN tile, 4 waves 2x2, BK=32 double-buffered 1-deep prefetch.
// ---------------------------------------------------------------------------
template<int BM, int BN, int MODE>
__device__ __forceinline__ void gemm_body(
    const short* __restrict__ A, const short* __restrict__ Bw,
    const float* __restrict__ biasv, void* __restrict__ dest,
    int M, int K, int Nw, int bx, int by, short* smem)
{
    constexpr int WTM = BM / 2, WTN = BN / 2;
    constexpr int TM = WTM / 16, TN = WTN / 16;
    short* As = smem;                    // [2][BM*32]
    short* Bs = smem + 2 * BM * 32;      // [2][BN*32]

    const int t    = threadIdx.x;
    const int lane = t & 63;
    const int w    = t >> 6;
    const int quad = lane >> 4, l15 = lane & 15;
    const int wm = w >> 1, wn = w & 1;
    const int m0 = bx * BM, n0 = by * BN;

    const int srow = lane >> 2;
    // swizzled source granule: lane fetches granule (lane&3)^((lane>>3)&3)
    const int scol = (((lane & 3) ^ ((lane >> 3) & 3))) * 8;
    const int xq   = (l15 >> 1) & 3;     // read-side un-swizzle

    v4f acc[TM][TN];
    #pragma unroll
    for (int i = 0; i < TM; ++i)
        #pragma unroll
        for (int j = 0; j < TN; ++j) acc[i][j] = (v4f){0.f, 0.f, 0.f, 0.f};

    const int NK = K >> 5;

    auto stage = [&](int buf, int kt) {
        #pragma unroll
        for (int u = 0; u < BM / 64; ++u) {
            const int e0 = (w * (BM / 64) + u) * 512;
            const int row = (e0 >> 5) + srow;
            async_copy16(A + (size_t)(m0 + row) * K + kt + scol,
                         &As[buf * BM * 32 + e0]);
        }
        #pragma unroll
        for (int u = 0; u < BN / 64; ++u) {
            const int e0 = (w * (BN / 64) + u) * 512;
            const int row = (e0 >> 5) + srow;
            async_copy16(Bw + (size_t)(n0 + row) * K + kt + scol,
                         &Bs[buf * BN * 32 + e0]);
        }
    };

    stage(0, 0);

    for (int it = 0; it < NK; ++it) {
        __syncthreads();
        if (it + 1 < NK) stage((it + 1) & 1, (it + 1) << 5);

        const int buf = it & 1;
        v8s af[TM], bfr[TN];
        #pragma unroll
        for (int i = 0; i < TM; ++i)
            af[i] = *(const v8s*)&As[buf * BM * 32 +
                                     (wm * WTM + i * 16 + l15) * 32 + (quad ^ xq) * 8];
        #pragma unroll
        for (int j = 0; j < TN; ++j)
            bfr[j] = *(const v8s*)&Bs[buf * BN * 32 +
                                      (wn * WTN + j * 16 + l15) * 32 + (quad ^ xq) * 8];
        #pragma unroll
        for (int i = 0; i < TM; ++i)
            #pragma unroll
            for (int j = 0; j < TN; ++j)
                acc[i][j] = __builtin_amdgcn_mfma_f32_16x16x32_bf16(
                    af[i], bfr[j], acc[i][j], 0, 0, 0);
    }

    #pragma unroll
    for (int i = 0; i < TM; ++i) {
        #pragma unroll
        for (int j = 0; j < TN; ++j) {
            const int mb = m0 + wm * WTM + i * 16 + quad * 4;   // row of rr=0
            const int n  = n0 + wn * WTN + j * 16 + l15;
            float vals[4];
            if (MODE == MODE_VT) {
                #pragma unroll
                for (int rr = 0; rr < 4; ++rr) vals[rr] = acc[i][j][rr] + biasv[mb + rr];
            } else {
                #pragma unroll
                for (int rr = 0; rr < 4; ++rr) vals[rr] = acc[i][j][rr] + biasv[n];
            }

            if (MODE == MODE_QK) {
                // fold softmax scale into Q (q-plane blocks have n0 < 256)
                if (n0 < 256) {
                    #pragma unroll
                    for (int rr = 0; rr < 4; ++rr) vals[rr] *= CS;
                }
                const int b = mb >> 10, ii0 = mb & 1023;
                const int plane = n >> 8, nn = n & 255;
                const int h = nn >> 5, d = nn & 31;
                #pragma unroll
                for (int rr = 0; rr < 4; ++rr)
                    ((short*)dest)[(size_t)plane * SZH +
                        (((size_t)(b * CH + h)) * CN + ii0 + rr) * CDH + d] =
                        f2bf(vals[rr]);
            } else if (MODE == MODE_VT) {
                // c-order column permutation within each 64-token tile:
                // c = ((j&15)<<2) | ((j>>4)&3)  so attn's P pairs (j, j+16)
                // are memory-adjacent.  Same 128B window -> still coalesced.
                const int b = n >> 10, ii = n & 1023;
                const int iip = (ii & ~63) | ((ii & 15) << 2) | ((ii >> 4) & 3);
                #pragma unroll
                for (int rr = 0; rr < 4; ++rr) {
                    const int m = mb + rr;
                    const int r2 = m >> 8, hd = m & 255;
                    const int h = hd >> 5, d = hd & 31;
                    ((short*)dest)[2 * SZH +
                        (((size_t)(r2 * 64 + b * CH + h)) * CDH + d) * CN + iip] =
                        f2bf(vals[rr]);
                }
            } else { // MODE_FFN1: tanh-gelu -> bf16 (x*E/(E+1))
                #pragma unroll
                for (int rr = 0; rr < 4; ++rr) {
                    const size_t idx = (size_t)(mb + rr) * Nw + n;
                    const float xx = vals[rr];
                    const float E = exp2f(2.302217f * (xx + 0.044715f * xx * xx * xx));
                    ((short*)dest)[idx] = f2bf(xx * E / (E + 1.f));
                }
            }
        }
    }
}

template<int BM, int BN, int MODE>
__global__ __launch_bounds__(256)
void gemm_mfma(const short* __restrict__ A, const short* __restrict__ Bw,
               const float* __restrict__ biasv, void* __restrict__ dest,
               int M, int K, int Nw)
{
    extern __shared__ short smem[];
    gemm_body<BM, BN, MODE>(A, Bw, biasv, dest, M, K, Nw,
                            blockIdx.x, blockIdx.y, smem);
}

// ---------------------------------------------------------------------------
// Fused projection dispatch: blocks 0..511 = QK (8192x512), 512..1535 = V^T,
// 1536..2047 = adj int32 -> 4-BIT pack in c-order (nibble pairs (j, j+16)).
// ---------------------------------------------------------------------------
__global__ __launch_bounds__(256)
void proj_kernel(const short* __restrict__ src_bf, const short* __restrict__ wqkvT,
                 const float* __restrict__ bpack, short* __restrict__ qkv,
                 const int* __restrict__ adj, unsigned char* __restrict__ adj4)
{
    extern __shared__ short smem[];
    const int g = blockIdx.x;
    if (g < 512) {
        gemm_body<64, 128, MODE_QK>(src_bf, wqkvT, bpack, qkv,
                                    8192, 256, 512, g >> 2, g & 3, smem);
    } else if (g < 1536) {
        const int h2 = g - 512;
        gemm_body<64, 128, MODE_VT>(wqkvT + 512 * 256, src_bf, bpack + 512,
                                    qkv, 1024, 256, 8192, h2 & 15, h2 >> 4, smem);
    } else {
        // c-order 4-bit pack: output dword m of tile T holds nibbles for
        // j = {2m,2m+16,2m+32,2m+48, 2m+1,2m+17,2m+33,2m+49}
        const int nout = CB * CN * CN / 8;           // 1M dwords
        for (int i = (g - 1536) * 256 + threadIdx.x; i < nout; i += 512 * 256) {
            const int m   = i & 7;
            const int T   = (i >> 3) & 15;
            const int row = i >> 7;
            const int* p = adj + (size_t)row * CN + T * 64 + 2 * m;
            const int2 q0 = *(const int2*)(p);
            const int2 q1 = *(const int2*)(p + 16);
            const int2 q2 = *(const int2*)(p + 32);
            const int2 q3 = *(const int2*)(p + 48);
            const unsigned pk =
                (unsigned)(q0.x & 0xf)         | ((unsigned)(q1.x & 0xf) << 4)  |
                ((unsigned)(q2.x & 0xf) << 8)  | ((unsigned)(q3.x & 0xf) << 12) |
                ((unsigned)(q0.y & 0xf) << 16) | ((unsigned)(q1.y & 0xf) << 20) |
                ((unsigned)(q2.y & 0xf) << 24) | ((unsigned)(q3.y & 0xf) << 28);
            ((unsigned*)adj4)[i] = pk;
        }
    }
}

// ---------------------------------------------------------------------------
// FUSED GEMM + bias + residual + LayerNorm, BM=16 -> 512 blocks (2/CU).
// OUTF: write fp32 result; OUTB: write bf16 result; ADDBF: residual is bf16.
// ---------------------------------------------------------------------------
template<bool OUTF, bool OUTB, bool ADDBF>
__global__ __launch_bounds__(256)
void gemm_ln32(const short* __restrict__ A, const short* __restrict__ Bw,
               const float* __restrict__ biasv, const void* __restrict__ addp,
               const float* __restrict__ gw, const float* __restrict__ be,
               float* __restrict__ outf, short* __restrict__ outb, int K)
{
    __shared__ short As[2][16 * 32];
    __shared__ short Bs[2][256 * 32];
    __shared__ float redS[16][4], redQ[16][4];

    const int t    = threadIdx.x;
    const int lane = t & 63;
    const int w    = t >> 6;          // wave -> column quarter (64 cols)
    const int quad = lane >> 4, l15 = lane & 15;
    const int m0   = blockIdx.x * 16;

    const int srow = lane >> 2;
    const int scol = (((lane & 3) ^ ((lane >> 3) & 3))) * 8;  // swizzled source
    const int xq   = (l15 >> 1) & 3;                          // read un-swizzle

    v4f acc[4];
    #pragma unroll
    for (int j = 0; j < 4; ++j) acc[j] = (v4f){0.f, 0.f, 0.f, 0.f};

    const int NK = K >> 5;

    auto stage = [&](int buf, int kt) {
        if (t < 64)   // A: 16 rows, one DMA per lane of wave 0
            async_copy16(A + (size_t)(m0 + (t >> 2)) * K + kt +
                             (((t & 3) ^ ((t >> 3) & 3))) * 8,
                         &As[buf][t * 8]);
        #pragma unroll
        for (int u = 0; u < 4; ++u) {   // B: 256 rows, 4 DMAs/thread
            const int e0 = (w * 4 + u) * 512;
            async_copy16(Bw + (size_t)((e0 >> 5) + srow) * K + kt + scol,
                         &Bs[buf][e0]);
        }
    };

    stage(0, 0);

    for (int it = 0; it < NK; ++it) {
        __syncthreads();
        if (it + 1 < NK) stage((it + 1) & 1, (it + 1) << 5);

        const int buf = it & 1;
        const v8s af = *(const v8s*)&As[buf][l15 * 32 + (quad ^ xq) * 8];
        #pragma unroll
        for (int j = 0; j < 4; ++j) {
            const v8s bfr = *(const v8s*)&Bs[buf][(w * 64 + 16 * j + l15) * 32 + (quad ^ xq) * 8];
            acc[j] = __builtin_amdgcn_mfma_f32_16x16x32_bf16(af, bfr, acc[j], 0, 0, 0);
        }
    }

    float v[4][4];
    #pragma unroll
    for (int rr = 0; rr < 4; ++rr) {
        const int row = m0 + quad * 4 + rr;
        float s = 0.f, sq = 0.f;
        #pragma unroll
        for (int j = 0; j < 4; ++j) {
            const int n = w * 64 + 16 * j + l15;
            const size_t idx = (size_t)row * CD + n;
            const float addv = ADDBF ? bf2f(((const short*)addp)[idx])
                                     : ((const float*)addp)[idx];
            const float x = acc[j][rr] + biasv[n] + addv;
            v[rr][j] = x;
            s += x; sq += x * x;
        }
        #pragma unroll
        for (int off = 1; off < 16; off <<= 1) {
            s  += __shfl_xor(s, off);
            sq += __shfl_xor(sq, off);
        }
        if (l15 == 0) {
            redS[quad * 4 + rr][w] = s;
            redQ[quad * 4 + rr][w] = sq;
        }
    }
    __syncthreads();

    #pragma unroll
    for (int rr = 0; rr < 4; ++rr) {
        const int r16 = quad * 4 + rr;
        const int row = m0 + r16;
        const float s  = (redS[r16][0] + redS[r16][1]) + (redS[r16][2] + redS[r16][3]);
        const float sq = (redQ[r16][0] + redQ[r16][1]) + (redQ[r16][2] + redQ[r16][3]);
        const float mean = s * (1.f / CD);
        const float var  = sq * (1.f / CD) - mean * mean;
        const float rstd = rsqrtf(var + CEPS);
        #pragma unroll
        for (int j = 0; j < 4; ++j) {
            const int n = w * 64 + 16 * j + l15;
            const float y = (v[rr][j] - mean) * rstd * gw[n] + be[n];
            if (OUTF) outf[(size_t)row * CD + n] = y;
            if (OUTB) outb[(size_t)row * CD + n] = f2bf(y);
        }
    }
}

// ---------------------------------------------------------------------------
// Prep: src->bf16, weight transposes via 64x64 LDS tiles, biases packed.
// ---------------------------------------------------------------------------
__global__ __launch_bounds__(256)
void prep(const float* __restrict__ src,
          const float* __restrict__ Wq, const float* __restrict__ Wk,
          const float* __restrict__ Wv, const float* __restrict__ Wo,
          const float* __restrict__ W1, const float* __restrict__ W2,
          const float* __restrict__ bq, const float* __restrict__ bk,
          const float* __restrict__ bv, const float* __restrict__ bo,
          const float* __restrict__ b1, const float* __restrict__ b2,
          short* __restrict__ src_bf,
          short* __restrict__ wqkvT, short* __restrict__ woT,
          short* __restrict__ w1T, short* __restrict__ w2T,
          float* __restrict__ bpack)
{
    __shared__ float tile[64][65];
    const int bx = blockIdx.x, t = threadIdx.x;
    if (bx < 2048) {                                   // src cast: 512K float4
        const int i = bx * 256 + t;
        const float4 v = ((const float4*)src)[i];
        short4 o;
        o.x = f2bf(v.x); o.y = f2bf(v.y); o.z = f2bf(v.z); o.w = f2bf(v.w);
        ((short4*)src_bf)[i] = o;
    } else if (bx < 2288) {                            // weight transposes
        const int tt = bx - 2048;
        const float* S; short* D;
        int Sstride, Dstride, k0, srccol, dstrow;
        if (tt < 96) {                                 // wqkv: 24x4 tiles
            const int tk = tt & 3, tn = tt >> 2;
            const int ng = tn * 64;
            Sstride = 256; Dstride = 256; k0 = tk * 64;
            dstrow = tn * 64; D = wqkvT;
            if (ng < 256)      { S = Wq; srccol = ng; }
            else if (ng < 512) { S = Wk; srccol = ng - 256; }
            else { const int r = (ng - 512) >> 8;
                   S = Wv + (size_t)r * 65536; srccol = (ng - 512) & 255; }
        } else if (tt < 112) {                         // wo: 4x4
            const int u = tt - 96, tk = u & 3, tn = u >> 2;
            S = Wo; Sstride = 256; D = woT; Dstride = 256;
            k0 = tk * 64; srccol = tn * 64; dstrow = tn * 64;
        } else if (tt < 176) {                         // w1: 16x4
            const int u = tt - 112, tk = u & 3, tn = u >> 2;
            S = W1; Sstride = 1024; D = w1T; Dstride = 256;
            k0 = tk * 64; srccol = tn * 64; dstrow = tn * 64;
        } else {                                       // w2: 4x16
            const int u = tt - 176, tk = u & 15, tn = u >> 4;
            S = W2; Sstride = 256; D = w2T; Dstride = 1024;
            k0 = tk * 64; srccol = tn * 64; dstrow = tn * 64;
        }
        #pragma unroll
        for (int u2 = 0; u2 < 4; ++u2) {               // coalesced read
            const int kl = (t >> 4) + u2 * 16;
            const int nl = (t & 15) * 4;
            const float4 v = *(const float4*)&S[(size_t)(k0 + kl) * Sstride + srccol + nl];
            tile[kl][nl + 0] = v.x; tile[kl][nl + 1] = v.y;
            tile[kl][nl + 2] = v.z; tile[kl][nl + 3] = v.w;
        }
        __syncthreads();
        #pragma unroll
        for (int u2 = 0; u2 < 4; ++u2) {               // coalesced write
            const int nl = (t >> 4) + u2 * 16;
            const int kl = (t & 15) * 4;
            short4 o;
            o.x = f2bf(tile[kl + 0][nl]); o.y = f2bf(tile[kl + 1][nl]);
            o.z = f2bf(tile[kl + 2][nl]); o.w = f2bf(tile[kl + 3][nl]);
            *(short4*)&D[(size_t)(dstrow + nl) * Dstride + k0 + kl] = o;
        }
    } else {                                           // biases: 3072
        const int idx = (bx - 2288) * 256 + t;
        float bvv;
        if (idx < 256)       bvv = bq[idx];
        else if (idx < 512)  bvv = bk[idx - 256];
        else if (idx < 1536) bvv = bv[idx - 512];
        else if (idx < 1792) bvv = bo[idx - 1536];
        else if (idx < 2816) bvv = b1[idx - 1792];
        else                 bvv = b2[idx - 2816];
        bpack[idx] = bvv;
    }
}

// ---------------------------------------------------------------------------
// Fused relational attention.  j runs in c-order (c = ((j&15)<<2)|(j>>4)) on
// the PV side; K tile is bank-swizzled (source-granule XOR) so the kfrag
// ds_read_b128 is conflict-free; masks from packed-i16 arithmetic (no LUT).
// XCD-aware 1D grid: b = g & 7 keeps one batch's K/V/adj on one XCD's L2.
// ---------------------------------------------------------------------------
__global__ __launch_bounds__(256)
void attn_mfma(const short* __restrict__ qg, const short* __restrict__ kg,
               const short* __restrict__ vt, const unsigned char* __restrict__ adj4,
               short* __restrict__ outh)
{
    __shared__ __align__(16) short ks[2][64 * 32];      // K tiles (dbuf, DMA, swizzled)
    __shared__ __align__(16) short vtile[4][32][72];    // V^T tiles [r][d][c]
    __shared__ __align__(16) short ps[64][72];          // P tile [i][c] (16B-aligned rows)
    __shared__ __align__(16) unsigned char adjs[64][40];// packed adj [i][c/2]

    const int t    = threadIdx.x;
    const int lane = t & 63;
    const int w    = t >> 6;          // wave 0..3
    const int quad = lane >> 4;
    const int l15  = lane & 15;
    const int g    = blockIdx.x;      // 1D grid, XCD-aware decode
    const int b    = g & 7;           // same XCD for whole batch
    const int h    = (g >> 3) & 7;
    const int i0   = (g >> 6) * 64;
    const int bhh  = b * CH + h;
    const size_t bh = (size_t)bhh;

    const v8s qfrag = *(const v8s*)&qg[(bh * CN + i0 + 16 * w + l15) * CDH + quad * 8];

    v4f oacc[2];
    oacc[0] = (v4f){0.f, 0.f, 0.f, 0.f};
    oacc[1] = (v4f){0.f, 0.f, 0.f, 0.f};
    float plsum[4] = {0.f, 0.f, 0.f, 0.f};

    const int arow = 16 * w + l15;    // this lane's P/adj row (wave-private)

    const int srow = lane >> 2;            // K: row within wave-issue
    const int scol = (((lane & 3) ^ ((lane >> 3) & 3))) * 8;  // swizzled K source
    const int xq   = (l15 >> 1) & 3;       // kfrag read un-swizzle
    const int vd0  = lane >> 3;            // V: base d (0..7), +8*it
    const int vc   = (lane & 7) * 8;       // V: c chunk
    const short* vplane = vt + (((size_t)(w * 64 + bhh)) * CDH) * CN;  // wave w -> relation w
    const unsigned char* adjg =
        adj4 + ((size_t)(b * CN) + i0 + (t >> 2)) * (CN / 2) + (t & 3) * 8;

    v8s vpre[4];
    int2 apre;

    // ---- prologue: prefetch tile 0 ----
    async_copy16(kg + (bh * CN + 16 * w + srow) * CDH + scol,
                 &ks[0][(16 * w + srow) * 32]);
    #pragma unroll
    for (int it = 0; it < 4; ++it)
        vpre[it] = *(const v8s*)&vplane[(size_t)(vd0 + 8 * it) * CN + vc];
    apre = *(const int2*)adjg;

    for (int jt = 0; jt < 16; ++jt) {
        __syncthreads();   // A: prev compute done; this tile's loads landed

        #pragma unroll
        for (int it = 0; it < 4; ++it)
            *(v8s*)&vtile[w][vd0 + 8 * it][vc] = vpre[it];
        *(int2*)&adjs[t >> 2][(t & 3) * 8] = apre;
        __syncthreads();   // B: tile published

        if (jt + 1 < 16) {
            const int j1 = (jt + 1) * 64;
            async_copy16(kg + (bh * CN + j1 + 16 * w + srow) * CDH + scol,
                         &ks[(jt + 1) & 1][(16 * w + srow) * 32]);
            #pragma unroll
            for (int it = 0; it < 4; ++it)
                vpre[it] = *(const v8s*)&vplane[(size_t)(vd0 + 8 * it) * CN + j1 + vc];
            apre = *(const int2*)(adjg + (jt + 1) * 32);
        }

        // ---- scores: 4 MFMA per wave (Q pre-scaled by cs) ----
        const short* ksb = ks[jt & 1];
        v4f sacc[4];
        #pragma unroll
        for (int jb = 0; jb < 4; ++jb) {
            const v8s kfrag = *(const v8s*)&ksb[(16 * jb + l15) * 32 + (quad ^ xq) * 8];
            sacc[jb] = __builtin_amdgcn_mfma_f32_16x16x32_bf16(
                qfrag, kfrag, (v4f){0.f, 0.f, 0.f, 0.f}, 0, 0, 0);
        }

        // ---- fixed-max softmax; pack pairs in c-order, one b64 write/rr ----
        #pragma unroll
        for (int rr = 0; rr < 4; ++rr) {
            const int prow = 16 * w + quad * 4 + rr;
            float p[4];
            #pragma unroll
            for (int jb = 0; jb < 4; ++jb) p[jb] = exp2f(sacc[jb][rr]);
            plsum[rr] += (p[0] + p[1]) + (p[2] + p[3]);
            const unsigned lo = cvtpk_bf16(p[0], p[1]);   // c = 4*l15+0, +1
            const unsigned hi = cvtpk_bf16(p[2], p[3]);   // c = 4*l15+2, +3
            *(uint2*)&ps[prow][4 * l15] = make_uint2(lo, hi);
        }

        // ---- PV: packed-i16 arithmetic masks (no LUT, no LDS gather) ----
        #pragma unroll
        for (int kb = 0; kb < 2; ++kb) {
            const int4 praw = *(const int4*)&ps[arow][32 * kb + quad * 8];
            const unsigned ab32 = *(const unsigned*)&adjs[arow][16 * kb + quad * 4];
            const unsigned P[4] = {(unsigned)praw.x, (unsigned)praw.y,
                                   (unsigned)praw.z, (unsigned)praw.w};
            unsigned pf[4][4];
            #pragma unroll
            for (int u = 0; u < 4; ++u) {
                // splat byte u into both halves, isolate (v0 | v1<<4 in hi)
                const unsigned sel = 0x0c000c00u | (unsigned)u | ((unsigned)u << 16);
                const unsigned a2 = __builtin_amdgcn_perm(ab32, ab32, sel) & 0x00F0000Fu;
                #pragma unroll
                for (int r = 0; r < 4; ++r) {
                    const unsigned x = a2 ^ ((unsigned)r | ((unsigned)r << 20));
                    unsigned tt, mm;
                    // per-half: (half==0) -> 0xffff else 0
                    asm("v_pk_add_i16 %0, %1, %2"
                        : "=v"(tt) : "v"(x), "v"(0xffffffffu));
                    asm("v_pk_ashrrev_i16 %0, %1, %2"
                        : "=v"(mm) : "v"(0x000f000fu), "v"(tt));
                    pf[r][u] = P[u] & mm;
                }
            }
            #pragma unroll
            for (int r = 0; r < 4; ++r) {
                const v8s pfr = __builtin_bit_cast(v8s,
                    make_uint4(pf[r][0], pf[r][1], pf[r][2], pf[r][3]));
                #pragma unroll
                for (int cb = 0; cb < 2; ++cb) {
                    const v8s vfrag = *(const v8s*)&vtile[r][16 * cb + l15][32 * kb + quad * 8];
                    oacc[cb] = __builtin_amdgcn_mfma_f32_16x16x32_bf16(
                        pfr, vfrag, oacc[cb], 0, 0, 0);
                }
            }
        }
    }

    // ---- epilogue ----
    #pragma unroll
    for (int rr = 0; rr < 4; ++rr) {
        float l = plsum[rr];
        #pragma unroll
        for (int off = 1; off < 16; off <<= 1) l += __shfl_xor(l, off);
        const float inv = 1.f / l;
        const int row = i0 + 16 * w + quad * 4 + rr;
        #pragma unroll
        for (int cb = 0; cb < 2; ++cb)
            outh[((size_t)b * CN + row) * CD + h * CDH + 16 * cb + l15] =
                f2bf(oacc[cb][rr] * inv);
    }
}

// ---------------------------------------------------------------------------
extern "C" void kernel_launch(void* const* d_in, const int* in_sizes, int n_in,
                              void* d_out, int out_size, void* d_ws, size_t ws_size,
                              hipStream_t stream)
{
    const float* src = (const float*)d_in[0];
    const int*   adj = (const int*)d_in[1];
    const float* Wq  = (const float*)d_in[2];
    const float* bq  = (const float*)d_in[3];
    const float* Wk  = (const float*)d_in[4];
    const float* bk  = (const float*)d_in[5];
    const float* Wv  = (const float*)d_in[6];
    const float* bv  = (const float*)d_in[7];
    const float* Wo  = (const float*)d_in[8];
    const float* bo  = (const float*)d_in[9];
    const float* W1  = (const float*)d_in[10];
    const float* b1  = (const float*)d_in[11];
    const float* W2  = (const float*)d_in[12];
    const float* b2  = (const float*)d_in[13];
    const float* g1  = (const float*)d_in[14];
    const float* be1 = (const float*)d_in[15];
    const float* g2  = (const float*)d_in[16];
    const float* be2 = (const float*)d_in[17];
    float* out = (float*)d_out;

    char* wsb = (char*)d_ws;
    const size_t MB = (size_t)1 << 20;

    // workspace layout (42 MB with aliasing)
    unsigned char* adj4 = (unsigned char*)(wsb);            // [0,4) MB packed adj
    short* qkv_bf = (short*)(wsb + 8 * MB);                 // [8,32): q,k planes + vT
    short* src_bf = (short*)(wsb + 32 * MB);                // [32,36)
    short* wqkvT  = (short*)(wsb + 36 * MB);                // 768 KB
    short* woT    = (short*)(wsb + 36 * MB + 768 * 1024);   // 128 KB
    short* w1T    = (short*)(wsb + 36 * MB + 896 * 1024);   // 512 KB
    short* w2T    = (short*)(wsb + 36 * MB + 1408 * 1024);  // 512 KB
    float* bpack  = (float*)(wsb + 36 * MB + 1920 * 1024);  // 12 KB
    short* heads_bf = (short*)(wsb + 38 * MB);              // [38,42)
    short* x_bf   = (short*)(wsb + 32 * MB);                // reuse src_bf (LN1 out)
    short* h1_bf  = (short*)(wsb + 16 * MB);                // reuse vT (dead post-attn)

    const int M = CB * CN;        // 8192
    dim3 blk(256);

    // prep: src cast, coalesced weight transposes, biases (2300 blocks)
    prep<<<dim3(2300), blk, 0, stream>>>(src, Wq, Wk, Wv, Wo, W1, W2,
        bq, bk, bv, bo, b1, b2, src_bf, wqkvT, woT, w1T, w2T, bpack);

    // fused QK + V^T projection + c-order 4-bit adj pack: 2048 blocks
    proj_kernel<<<dim3(2048), blk, 24576, stream>>>(
        src_bf, wqkvT, bpack, qkv_bf, adj, adj4);

    // fused relational MFMA attention (XCD-aware 1D grid) -> bf16 heads
    attn_mfma<<<dim3(1024), blk, 0, stream>>>(
        qkv_bf, qkv_bf + SZH, qkv_bf + 2 * SZH, adj4, heads_bf);

    // O-projection + bias + residual(src fp32) + LN1 -> x_bf bf16 only
    gemm_ln32<false, true, false><<<dim3(M / 16), blk, 0, stream>>>(
        heads_bf, woT, bpack + 1536, src, g1, be1, nullptr, x_bf, CD);

    // FFN1: 1024 blocks
    gemm_mfma<64, 128, MODE_FFN1><<<dim3(M / 64, CFF / 128), blk, 24576, stream>>>(
        x_bf, w1T, bpack + 1792, h1_bf, M, CD, CFF);

    // FFN2 + bias + residual(x_bf bf16) + LN2 -> out fp32
    gemm_ln32<true, false, true><<<dim3(M / 16), blk, 0, stream>>>(
        h1_bf, w2T, bpack + 2816, x_bf, g2, be2, out, nullptr, CFF);
}

// Round 3
// 228.972 us; speedup vs baseline: 1.0179x; 1.0179x over previous
//
#include <hip/hip_runtime.h>
#include <hip/hip_bf16.h>
#include <cmath>

// Problem constants (fixed by the reference)
constexpr int CB  = 8;     // batch
constexpr int CN  = 1024;  // sequence length
constexpr int CD  = 256;   // model dim
constexpr int CH  = 8;     // heads
constexpr int CDH = 32;    // head dim
constexpr int CR  = 4;     // relation types (adj value 4 = none)
constexpr int CFF = 1024;  // ffn dim
constexpr float CEPS = 1e-5f;
constexpr float CS = 0.25503480f;   // (1/sqrt(32)) * log2(e), folded into Q
constexpr size_t SZH = (size_t)CB * CH * CN * CDH;  // 2M: one head-plane

#define MODE_QK    0   // scatter bf16 q/k head-major planes, +bias (cols 0..511)
#define MODE_FFN1  2   // +bias, tanh-gelu -> bf16
#define MODE_VT    4   // V^T gemm (A=weight rows, B=src rows): c-order column store

typedef float v4f __attribute__((ext_vector_type(4)));
typedef short v8s __attribute__((ext_vector_type(8)));

static __device__ __forceinline__ short f2bf(float f) {
    unsigned u = __builtin_bit_cast(unsigned, f);
    u += 0x7fff + ((u >> 16) & 1);          // round-to-nearest-even
    return (short)(u >> 16);
}
static __device__ __forceinline__ float bf2f(short s) {
    unsigned u = ((unsigned)(unsigned short)s) << 16;
    return __builtin_bit_cast(float, u);
}
static __device__ __forceinline__ unsigned cvtpk_bf16(float lo, float hi) {
    unsigned r;
    asm("v_cvt_pk_bf16_f32 %0, %1, %2" : "=v"(r) : "v"(lo), "v"(hi));
    return r;
}

static __device__ __forceinline__ void async_copy16(const void* g, void* l) {
    __builtin_amdgcn_global_load_lds(
        (const __attribute__((address_space(1))) void*)g,
        (__attribute__((address_space(3))) void*)l, 16, 0, 0);
}

// ---------------------------------------------------------------------------
// bf16 MFMA GEMM body (device fn, dynamic LDS): epilogue(A[M,K] @ Bw[N,K])
// BM x BN tile, 4 waves 2x2, BK=32 double-buffered 1-deep prefetch.
// ---------------------------------------------------------------------------
template<int BM, int BN, int MODE>
__device__ __forceinline__ void gemm_body(
    const short* __restrict__ A, const short* __restrict__ Bw,
    const float* __restrict__ biasv, void* __restrict__ dest,
    int M, int K, int Nw, int bx, int by, short* smem)
{
    constexpr int WTM = BM / 2, WTN = BN / 2;
    constexpr int TM = WTM / 16, TN = WTN / 16;
    short* As = smem;                    // [2][BM*32]
    short* Bs = smem + 2 * BM * 32;      // [2][BN*32]

    const int t    = threadIdx.x;
    const int lane = t & 63;
    const int w    = t >> 6;
    const int quad = lane >> 4, l15 = lane & 15;
    const int wm = w >> 1, wn = w & 1;
    const int m0 = bx * BM, n0 = by * BN;

    const int srow = lane >> 2;
    const int scol = (lane & 3) * 8;

    v4f acc[TM][TN];
    #pragma unroll
    for (int i = 0; i < TM; ++i)
        #pragma unroll
        for (int j = 0; j < TN; ++j) acc[i][j] = (v4f){0.f, 0.f, 0.f, 0.f};

    const int NK = K >> 5;

    auto stage = [&](int buf, int kt) {
        #pragma unroll
        for (int u = 0; u < BM / 64; ++u) {
            const int e0 = (w * (BM / 64) + u) * 512;
            const int row = (e0 >> 5) + srow;
            async_copy16(A + (size_t)(m0 + row) * K + kt + scol,
                         &As[buf * BM * 32 + e0]);
        }
        #pragma unroll
        for (int u = 0; u < BN / 64; ++u) {
            const int e0 = (w * (BN / 64) + u) * 512;
            const int row = (e0 >> 5) + srow;
            async_copy16(Bw + (size_t)(n0 + row) * K + kt + scol,
                         &Bs[buf * BN * 32 + e0]);
        }
    };

    stage(0, 0);

    for (int it = 0; it < NK; ++it) {
        __syncthreads();
        if (it + 1 < NK) stage((it + 1) & 1, (it + 1) << 5);

        const int buf = it & 1;
        v8s af[TM], bfr[TN];
        #pragma unroll
        for (int i = 0; i < TM; ++i)
            af[i] = *(const v8s*)&As[buf * BM * 32 +
                                     (wm * WTM + i * 16 + l15) * 32 + quad * 8];
        #pragma unroll
        for (int j = 0; j < TN; ++j)
            bfr[j] = *(const v8s*)&Bs[buf * BN * 32 +
                                      (wn * WTN + j * 16 + l15) * 32 + quad * 8];
        #pragma unroll
        for (int i = 0; i < TM; ++i)
            #pragma unroll
            for (int j = 0; j < TN; ++j)
                acc[i][j] = __builtin_amdgcn_mfma_f32_16x16x32_bf16(
                    af[i], bfr[j], acc[i][j], 0, 0, 0);
    }

    #pragma unroll
    for (int i = 0; i < TM; ++i) {
        #pragma unroll
        for (int j = 0; j < TN; ++j) {
            const int mb = m0 + wm * WTM + i * 16 + quad * 4;   // row of rr=0
            const int n  = n0 + wn * WTN + j * 16 + l15;
            float vals[4];
            if (MODE == MODE_VT) {
                #pragma unroll
                for (int rr = 0; rr < 4; ++rr) vals[rr] = acc[i][j][rr] + biasv[mb + rr];
            } else {
                #pragma unroll
                for (int rr = 0; rr < 4; ++rr) vals[rr] = acc[i][j][rr] + biasv[n];
            }

            if (MODE == MODE_QK) {
                // fold softmax scale into Q (q-plane blocks have n0 < 256)
                if (n0 < 256) {
                    #pragma unroll
                    for (int rr = 0; rr < 4; ++rr) vals[rr] *= CS;
                }
                const int b = mb >> 10, ii0 = mb & 1023;
                const int plane = n >> 8, nn = n & 255;
                const int h = nn >> 5, d = nn & 31;
                #pragma unroll
                for (int rr = 0; rr < 4; ++rr)
                    ((short*)dest)[(size_t)plane * SZH +
                        (((size_t)(b * CH + h)) * CN + ii0 + rr) * CDH + d] =
                        f2bf(vals[rr]);
            } else if (MODE == MODE_VT) {
                // c-order column permutation within each 64-token tile:
                // c = ((j&15)<<2) | ((j>>4)&3)  so attn's P pairs (j, j+16)
                // are memory-adjacent.  Same 128B window -> still coalesced.
                const int b = n >> 10, ii = n & 1023;
                const int iip = (ii & ~63) | ((ii & 15) << 2) | ((ii >> 4) & 3);
                #pragma unroll
                for (int rr = 0; rr < 4; ++rr) {
                    const int m = mb + rr;
                    const int r2 = m >> 8, hd = m & 255;
                    const int h = hd >> 5, d = hd & 31;
                    ((short*)dest)[2 * SZH +
                        (((size_t)(r2 * 64 + b * CH + h)) * CDH + d) * CN + iip] =
                        f2bf(vals[rr]);
                }
            } else { // MODE_FFN1: tanh-gelu -> bf16 (x*E/(E+1))
                #pragma unroll
                for (int rr = 0; rr < 4; ++rr) {
                    const size_t idx = (size_t)(mb + rr) * Nw + n;
                    const float xx = vals[rr];
                    const float E = exp2f(2.302217f * (xx + 0.044715f * xx * xx * xx));
                    ((short*)dest)[idx] = f2bf(xx * E / (E + 1.f));
                }
            }
        }
    }
}

template<int BM, int BN, int MODE>
__global__ __launch_bounds__(256)
void gemm_mfma(const short* __restrict__ A, const short* __restrict__ Bw,
               const float* __restrict__ biasv, void* __restrict__ dest,
               int M, int K, int Nw)
{
    extern __shared__ short smem[];
    gemm_body<BM, BN, MODE>(A, Bw, biasv, dest, M, K, Nw,
                            blockIdx.x, blockIdx.y, smem);
}

// ---------------------------------------------------------------------------
// Fused projection dispatch: blocks 0..511 = QK (8192x512), 512..1535 = V^T,
// 1536..2047 = adj int32 -> 4-BIT pack in c-order (nibble pairs (j, j+16)).
// ---------------------------------------------------------------------------
__global__ __launch_bounds__(256)
void proj_kernel(const short* __restrict__ src_bf, const short* __restrict__ wqkvT,
                 const float* __restrict__ bpack, short* __restrict__ qkv,
                 const int* __restrict__ adj, unsigned char* __restrict__ adj4)
{
    extern __shared__ short smem[];
    const int g = blockIdx.x;
    if (g < 512) {
        gemm_body<64, 128, MODE_QK>(src_bf, wqkvT, bpack, qkv,
                                    8192, 256, 512, g >> 2, g & 3, smem);
    } else if (g < 1536) {
        const int h2 = g - 512;
        gemm_body<64, 128, MODE_VT>(wqkvT + 512 * 256, src_bf, bpack + 512,
                                    qkv, 1024, 256, 8192, h2 & 15, h2 >> 4, smem);
    } else {
        // c-order 4-bit pack: output dword m of tile T holds nibbles for
        // j = {2m,2m+16,2m+32,2m+48, 2m+1,2m+17,2m+33,2m+49}
        const int nout = CB * CN * CN / 8;           // 1M dwords
        for (int i = (g - 1536) * 256 + threadIdx.x; i < nout; i += 512 * 256) {
            const int m   = i & 7;
            const int T   = (i >> 3) & 15;
            const int row = i >> 7;
            const int* p = adj + (size_t)row * CN + T * 64 + 2 * m;
            const int2 q0 = *(const int2*)(p);
            const int2 q1 = *(const int2*)(p + 16);
            const int2 q2 = *(const int2*)(p + 32);
            const int2 q3 = *(const int2*)(p + 48);
            const unsigned pk =
                (unsigned)(q0.x & 0xf)         | ((unsigned)(q1.x & 0xf) << 4)  |
                ((unsigned)(q2.x & 0xf) << 8)  | ((unsigned)(q3.x & 0xf) << 12) |
                ((unsigned)(q0.y & 0xf) << 16) | ((unsigned)(q1.y & 0xf) << 20) |
                ((unsigned)(q2.y & 0xf) << 24) | ((unsigned)(q3.y & 0xf) << 28);
            ((unsigned*)adj4)[i] = pk;
        }
    }
}

// ---------------------------------------------------------------------------
// FUSED GEMM + bias + residual + LayerNorm, BM=16 -> 512 blocks (2/CU).
// OUTF: write fp32 result; OUTB: write bf16 result; ADDBF: residual is bf16.
// ---------------------------------------------------------------------------
template<bool OUTF, bool OUTB, bool ADDBF>
__global__ __launch_bounds__(256)
void gemm_ln32(const short* __restrict__ A, const short* __restrict__ Bw,
               const float* __restrict__ biasv, const void* __restrict__ addp,
               const float* __restrict__ gw, const float* __restrict__ be,
               float* __restrict__ outf, short* __restrict__ outb, int K)
{
    __shared__ short As[2][16 * 32];
    __shared__ short Bs[2][256 * 32];
    __shared__ float redS[16][4], redQ[16][4];

    const int t    = threadIdx.x;
    const int lane = t & 63;
    const int w    = t >> 6;          // wave -> column quarter (64 cols)
    const int quad = lane >> 4, l15 = lane & 15;
    const int m0   = blockIdx.x * 16;

    const int srow = lane >> 2;
    const int scol = (lane & 3) * 8;

    v4f acc[4];
    #pragma unroll
    for (int j = 0; j < 4; ++j) acc[j] = (v4f){0.f, 0.f, 0.f, 0.f};

    const int NK = K >> 5;

    auto stage = [&](int buf, int kt) {
        if (t < 64)   // A: 16 rows, one DMA per lane of wave 0
            async_copy16(A + (size_t)(m0 + (t >> 2)) * K + kt + (t & 3) * 8,
                         &As[buf][t * 8]);
        #pragma unroll
        for (int u = 0; u < 4; ++u) {   // B: 256 rows, 4 DMAs/thread
            const int e0 = (w * 4 + u) * 512;
            async_copy16(Bw + (size_t)((e0 >> 5) + srow) * K + kt + scol,
                         &Bs[buf][e0]);
        }
    };

    stage(0, 0);

    for (int it = 0; it < NK; ++it) {
        __syncthreads();
        if (it + 1 < NK) stage((it + 1) & 1, (it + 1) << 5);

        const int buf = it & 1;
        const v8s af = *(const v8s*)&As[buf][l15 * 32 + quad * 8];
        #pragma unroll
        for (int j = 0; j < 4; ++j) {
            const v8s bfr = *(const v8s*)&Bs[buf][(w * 64 + 16 * j + l15) * 32 + quad * 8];
            acc[j] = __builtin_amdgcn_mfma_f32_16x16x32_bf16(af, bfr, acc[j], 0, 0, 0);
        }
    }

    float v[4][4];
    #pragma unroll
    for (int rr = 0; rr < 4; ++rr) {
        const int row = m0 + quad * 4 + rr;
        float s = 0.f, sq = 0.f;
        #pragma unroll
        for (int j = 0; j < 4; ++j) {
            const int n = w * 64 + 16 * j + l15;
            const size_t idx = (size_t)row * CD + n;
            const float addv = ADDBF ? bf2f(((const short*)addp)[idx])
                                     : ((const float*)addp)[idx];
            const float x = acc[j][rr] + biasv[n] + addv;
            v[rr][j] = x;
            s += x; sq += x * x;
        }
        #pragma unroll
        for (int off = 1; off < 16; off <<= 1) {
            s  += __shfl_xor(s, off);
            sq += __shfl_xor(sq, off);
        }
        if (l15 == 0) {
            redS[quad * 4 + rr][w] = s;
            redQ[quad * 4 + rr][w] = sq;
        }
    }
    __syncthreads();

    #pragma unroll
    for (int rr = 0; rr < 4; ++rr) {
        const int r16 = quad * 4 + rr;
        const int row = m0 + r16;
        const float s  = (redS[r16][0] + redS[r16][1]) + (redS[r16][2] + redS[r16][3]);
        const float sq = (redQ[r16][0] + redQ[r16][1]) + (redQ[r16][2] + redQ[r16][3]);
        const float mean = s * (1.f / CD);
        const float var  = sq * (1.f / CD) - mean * mean;
        const float rstd = rsqrtf(var + CEPS);
        #pragma unroll
        for (int j = 0; j < 4; ++j) {
            const int n = w * 64 + 16 * j + l15;
            const float y = (v[rr][j] - mean) * rstd * gw[n] + be[n];
            if (OUTF) outf[(size_t)row * CD + n] = y;
            if (OUTB) outb[(size_t)row * CD + n] = f2bf(y);
        }
    }
}

// ---------------------------------------------------------------------------
// Prep: src->bf16, weight transposes via 64x64 LDS tiles, biases packed.
// ---------------------------------------------------------------------------
__global__ __launch_bounds__(256)
void prep(const float* __restrict__ src,
          const float* __restrict__ Wq, const float* __restrict__ Wk,
          const float* __restrict__ Wv, const float* __restrict__ Wo,
          const float* __restrict__ W1, const float* __restrict__ W2,
          const float* __restrict__ bq, const float* __restrict__ bk,
          const float* __restrict__ bv, const float* __restrict__ bo,
          const float* __restrict__ b1, const float* __restrict__ b2,
          short* __restrict__ src_bf,
          short* __restrict__ wqkvT, short* __restrict__ woT,
          short* __restrict__ w1T, short* __restrict__ w2T,
          float* __restrict__ bpack)
{
    __shared__ float tile[64][65];
    const int bx = blockIdx.x, t = threadIdx.x;
    if (bx < 2048) {                                   // src cast: 512K float4
        const int i = bx * 256 + t;
        const float4 v = ((const float4*)src)[i];
        short4 o;
        o.x = f2bf(v.x); o.y = f2bf(v.y); o.z = f2bf(v.z); o.w = f2bf(v.w);
        ((short4*)src_bf)[i] = o;
    } else if (bx < 2288) {                            // weight transposes
        const int tt = bx - 2048;
        const float* S; short* D;
        int Sstride, Dstride, k0, srccol, dstrow;
        if (tt < 96) {                                 // wqkv: 24x4 tiles
            const int tk = tt & 3, tn = tt >> 2;
            const int ng = tn * 64;
            Sstride = 256; Dstride = 256; k0 = tk * 64;
            dstrow = tn * 64; D = wqkvT;
            if (ng < 256)      { S = Wq; srccol = ng; }
            else if (ng < 512) { S = Wk; srccol = ng - 256; }
            else { const int r = (ng - 512) >> 8;
                   S = Wv + (size_t)r * 65536; srccol = (ng - 512) & 255; }
        } else if (tt < 112) {                         // wo: 4x4
            const int u = tt - 96, tk = u & 3, tn = u >> 2;
            S = Wo; Sstride = 256; D = woT; Dstride = 256;
            k0 = tk * 64; srccol = tn * 64; dstrow = tn * 64;
        } else if (tt < 176) {                         // w1: 16x4
            const int u = tt - 112, tk = u & 3, tn = u >> 2;
            S = W1; Sstride = 1024; D = w1T; Dstride = 256;
            k0 = tk * 64; srccol = tn * 64; dstrow = tn * 64;
        } else {                                       // w2: 4x16
            const int u = tt - 176, tk = u & 15, tn = u >> 4;
            S = W2; Sstride = 256; D = w2T; Dstride = 1024;
            k0 = tk * 64; srccol = tn * 64; dstrow = tn * 64;
        }
        #pragma unroll
        for (int u2 = 0; u2 < 4; ++u2) {               // coalesced read
            const int kl = (t >> 4) + u2 * 16;
            const int nl = (t & 15) * 4;
            const float4 v = *(const float4*)&S[(size_t)(k0 + kl) * Sstride + srccol + nl];
            tile[kl][nl + 0] = v.x; tile[kl][nl + 1] = v.y;
            tile[kl][nl + 2] = v.z; tile[kl][nl + 3] = v.w;
        }
        __syncthreads();
        #pragma unroll
        for (int u2 = 0; u2 < 4; ++u2) {               // coalesced write
            const int nl = (t >> 4) + u2 * 16;
            const int kl = (t & 15) * 4;
            short4 o;
            o.x = f2bf(tile[kl + 0][nl]); o.y = f2bf(tile[kl + 1][nl]);
            o.z = f2bf(tile[kl + 2][nl]); o.w = f2bf(tile[kl + 3][nl]);
            *(short4*)&D[(size_t)(dstrow + nl) * Dstride + k0 + kl] = o;
        }
    } else {                                           // biases: 3072
        const int idx = (bx - 2288) * 256 + t;
        float bvv;
        if (idx < 256)       bvv = bq[idx];
        else if (idx < 512)  bvv = bk[idx - 256];
        else if (idx < 1536) bvv = bv[idx - 512];
        else if (idx < 1792) bvv = bo[idx - 1536];
        else if (idx < 2816) bvv = b1[idx - 1792];
        else                 bvv = b2[idx - 2816];
        bpack[idx] = bvv;
    }
}

// ---------------------------------------------------------------------------
// Fused relational attention, single-barrier pipeline:
//  - V^T staged by global_load_lds into a 2-deep LDS ring (linear dest,
//    source-granule XOR swizzle gc^(d&7) -> conflict-free vfrag reads)
//  - K and adj read DIRECT from L2 into registers, prefetched 1 tile ahead
//  - P transpose through granule-swizzled ps[64][64] (wave-private rows)
//  - masks from packed-i16 arithmetic; j in c-order (V/adj stored c-order)
// One __syncthreads per j-tile (vtl ring protection only).
// XCD-aware 1D grid: b = g & 7 keeps one batch's K/V/adj on one XCD's L2.
// ---------------------------------------------------------------------------
__global__ __launch_bounds__(256, 4)
void attn_mfma(const short* __restrict__ qg, const short* __restrict__ kg,
               const short* __restrict__ vt, const unsigned char* __restrict__ adj4,
               short* __restrict__ outh)
{
    __shared__ __align__(16) short vtl[2][8192];  // [buf][r*2048 + d*64 + gc*8]
    __shared__ __align__(16) short ps[4096];      // [row*64 + (gc^(row&7))*8]

    const int t    = threadIdx.x;
    const int lane = t & 63;
    const int w    = t >> 6;          // wave 0..3
    const int quad = lane >> 4;
    const int l15  = lane & 15;
    const int g    = blockIdx.x;      // 1D grid, XCD-aware decode
    const int b    = g & 7;           // same XCD for whole batch
    const int h    = (g >> 3) & 7;
    const int i0   = (g >> 6) * 64;
    const int bhh  = b * CH + h;
    const size_t bh = (size_t)bhh;

    const v8s qfrag = *(const v8s*)&qg[(bh * CN + i0 + 16 * w + l15) * CDH + quad * 8];

    // V DMA sources: thread t stages granule gl = t + 256u; LDS granule
    // (r,d,gc) holds global granule gc^(d&7) of V^T row (r,d) in this j-tile.
    const short* vsrc[4];
    #pragma unroll
    for (int u = 0; u < 4; ++u) {
        const int gl = t + 256 * u;
        const int r = gl >> 8, d = (gl >> 3) & 31, gc = gl & 7;
        vsrc[u] = vt + ((size_t)(r * 64 + bhh) * CDH + d) * CN + (gc ^ (d & 7)) * 8;
    }
    // K direct: row (jt*64 + 16jb + l15), col quad*8
    const short* kbase = kg + (bh * CN + l15) * CDH + quad * 8;
    // adj direct: row i0+16w+l15, dword (4kb+quad) of 32B tile slice
    const unsigned char* abase =
        adj4 + ((size_t)(b * CN) + i0 + 16 * w + l15) * (CN / 2) + quad * 4;

    v4f oacc[2];
    oacc[0] = (v4f){0.f, 0.f, 0.f, 0.f};
    oacc[1] = (v4f){0.f, 0.f, 0.f, 0.f};
    float plsum[4] = {0.f, 0.f, 0.f, 0.f};
    const int arow = 16 * w + l15;
    const int psw  = (l15 & 7) * 8;        // read-side granule XOR (pre-scaled)

    // ---- prologue: prefetch tile 0 ----
    #pragma unroll
    for (int u = 0; u < 4; ++u)
        async_copy16(vsrc[u], &vtl[0][(t + 256 * u) * 8]);
    v8s kpre[4];
    #pragma unroll
    for (int jb = 0; jb < 4; ++jb)
        kpre[jb] = *(const v8s*)(kbase + (16 * jb) * CDH);
    unsigned apre0 = *(const unsigned*)(abase);
    unsigned apre1 = *(const unsigned*)(abase + 16);

    for (int jt = 0; jt < 16; ++jt) {
        __syncthreads();   // vtl[jt&1] staged (DMAs issued last iter); other buf free
        const int p = jt & 1;

        // ---- QK from register K (Q pre-scaled by cs) ----
        v4f sacc[4];
        #pragma unroll
        for (int jb = 0; jb < 4; ++jb)
            sacc[jb] = __builtin_amdgcn_mfma_f32_16x16x32_bf16(
                qfrag, kpre[jb], (v4f){0.f, 0.f, 0.f, 0.f}, 0, 0, 0);

        // ---- issue prefetches for tile jt+1 (wrap harmless on last iter) ----
        const unsigned a0 = apre0, a1 = apre1;
        const int jn = (jt + 1) & 15;
        #pragma unroll
        for (int u = 0; u < 4; ++u)
            async_copy16(vsrc[u] + jn * 64, &vtl[p ^ 1][(t + 256 * u) * 8]);
        #pragma unroll
        for (int jb = 0; jb < 4; ++jb)
            kpre[jb] = *(const v8s*)(kbase + (jn * 64 + 16 * jb) * CDH);
        apre0 = *(const unsigned*)(abase + jn * 32);
        apre1 = *(const unsigned*)(abase + jn * 32 + 16);

        // ---- fixed-max softmax -> ps (granule-swizzled, wave-private) ----
        #pragma unroll
        for (int rr = 0; rr < 4; ++rr) {
            const int prow = 16 * w + quad * 4 + rr;
            float pv[4];
            #pragma unroll
            for (int jb = 0; jb < 4; ++jb) pv[jb] = exp2f(sacc[jb][rr]);
            plsum[rr] += (pv[0] + pv[1]) + (pv[2] + pv[3]);
            const unsigned lo = cvtpk_bf16(pv[0], pv[1]);   // c = 4*l15+0, +1
            const unsigned hi = cvtpk_bf16(pv[2], pv[3]);   // c = 4*l15+2, +3
            const int off = prow * 64 + (((l15 >> 1) ^ (prow & 7)) * 8) + (l15 & 1) * 4;
            *(uint2*)&ps[off] = make_uint2(lo, hi);
        }

        // ---- PV: packed-i16 arithmetic masks, vfrag from swizzled vtl ----
        #pragma unroll
        for (int kb = 0; kb < 2; ++kb) {
            const int4 praw = *(const int4*)&ps[arow * 64 + (((4 * kb + quad) * 8) ^ psw)];
            const unsigned ab32 = kb ? a1 : a0;
            const unsigned P[4] = {(unsigned)praw.x, (unsigned)praw.y,
                                   (unsigned)praw.z, (unsigned)praw.w};
            unsigned pf[4][4];
            #pragma unroll
            for (int u = 0; u < 4; ++u) {
                // splat byte u into both halves, isolate (v0 | v1<<4 in hi)
                const unsigned sel = 0x0c000c00u | (unsigned)u | ((unsigned)u << 16);
                const unsigned a2 = __builtin_amdgcn_perm(ab32, ab32, sel) & 0x00F0000Fu;
                #pragma unroll
                for (int r = 0; r < 4; ++r) {
                    const unsigned x = a2 ^ ((unsigned)r | ((unsigned)r << 20));
                    unsigned tt, mm;
                    // per-half: (half==0) -> 0xffff else 0
                    asm("v_pk_add_i16 %0, %1, %2"
                        : "=v"(tt) : "v"(x), "v"(0xffffffffu));
                    asm("v_pk_ashrrev_i16 %0, %1, %2"
                        : "=v"(mm) : "v"(0x000f000fu), "v"(tt));
                    pf[r][u] = P[u] & mm;
                }
            }
            #pragma unroll
            for (int r = 0; r < 4; ++r) {
                const v8s pfr = __builtin_bit_cast(v8s,
                    make_uint4(pf[r][0], pf[r][1], pf[r][2], pf[r][3]));
                #pragma unroll
                for (int cb = 0; cb < 2; ++cb) {
                    const v8s vfrag = *(const v8s*)&vtl[p][r * 2048 +
                        (16 * cb + l15) * 64 + (((4 * kb + quad) * 8) ^ psw)];
                    oacc[cb] = __builtin_amdgcn_mfma_f32_16x16x32_bf16(
                        pfr, vfrag, oacc[cb], 0, 0, 0);
                }
            }
        }
    }

    // ---- epilogue ----
    #pragma unroll
    for (int rr = 0; rr < 4; ++rr) {
        float l = plsum[rr];
        #pragma unroll
        for (int off = 1; off < 16; off <<= 1) l += __shfl_xor(l, off);
        const float inv = 1.f / l;
        const int row = i0 + 16 * w + quad * 4 + rr;
        #pragma unroll
        for (int cb = 0; cb < 2; ++cb)
            outh[((size_t)b * CN + row) * CD + h * CDH + 16 * cb + l15] =
                f2bf(oacc[cb][rr] * inv);
    }
}

// ---------------------------------------------------------------------------
extern "C" void kernel_launch(void* const* d_in, const int* in_sizes, int n_in,
                              void* d_out, int out_size, void* d_ws, size_t ws_size,
                              hipStream_t stream)
{
    const float* src = (const float*)d_in[0];
    const int*   adj = (const int*)d_in[1];
    const float* Wq  = (const float*)d_in[2];
    const float* bq  = (const float*)d_in[3];
    const float* Wk  = (const float*)d_in[4];
    const float* bk  = (const float*)d_in[5];
    const float* Wv  = (const float*)d_in[6];
    const float* bv  = (const float*)d_in[7];
    const float* Wo  = (const float*)d_in[8];
    const float* bo  = (const float*)d_in[9];
    const float* W1  = (const float*)d_in[10];
    const float* b1  = (const float*)d_in[11];
    const float* W2  = (const float*)d_in[12];
    const float* b2  = (const float*)d_in[13];
    const float* g1  = (const float*)d_in[14];
    const float* be1 = (const float*)d_in[15];
    const float* g2  = (const float*)d_in[16];
    const float* be2 = (const float*)d_in[17];
    float* out = (float*)d_out;

    char* wsb = (char*)d_ws;
    const size_t MB = (size_t)1 << 20;

    // workspace layout (42 MB with aliasing)
    unsigned char* adj4 = (unsigned char*)(wsb);            // [0,4) MB packed adj
    short* qkv_bf = (short*)(wsb + 8 * MB);                 // [8,32): q,k planes + vT
    short* src_bf = (short*)(wsb + 32 * MB);                // [32,36)
    short* wqkvT  = (short*)(wsb + 36 * MB);                // 768 KB
    short* woT    = (short*)(wsb + 36 * MB + 768 * 1024);   // 128 KB
    short* w1T    = (short*)(wsb + 36 * MB + 896 * 1024);   // 512 KB
    short* w2T    = (short*)(wsb + 36 * MB + 1408 * 1024);  // 512 KB
    float* bpack  = (float*)(wsb + 36 * MB + 1920 * 1024);  // 12 KB
    short* heads_bf = (short*)(wsb + 38 * MB);              // [38,42)
    short* x_bf   = (short*)(wsb + 32 * MB);                // reuse src_bf (LN1 out)
    short* h1_bf  = (short*)(wsb + 16 * MB);                // reuse vT (dead post-attn)

    const int M = CB * CN;        // 8192
    dim3 blk(256);

    // prep: src cast, coalesced weight transposes, biases (2300 blocks)
    prep<<<dim3(2300), blk, 0, stream>>>(src, Wq, Wk, Wv, Wo, W1, W2,
        bq, bk, bv, bo, b1, b2, src_bf, wqkvT, woT, w1T, w2T, bpack);

    // fused QK + V^T projection + c-order 4-bit adj pack: 2048 blocks
    proj_kernel<<<dim3(2048), blk, 24576, stream>>>(
        src_bf, wqkvT, bpack, qkv_bf, adj, adj4);

    // fused relational MFMA attention (XCD-aware 1D grid) -> bf16 heads
    attn_mfma<<<dim3(1024), blk, 0, stream>>>(
        qkv_bf, qkv_bf + SZH, qkv_bf + 2 * SZH, adj4, heads_bf);

    // O-projection + bias + residual(src fp32) + LN1 -> x_bf bf16 only
    gemm_ln32<false, true, false><<<dim3(M / 16), blk, 0, stream>>>(
        heads_bf, woT, bpack + 1536, src, g1, be1, nullptr, x_bf, CD);

    // FFN1: 1024 blocks
    gemm_mfma<64, 128, MODE_FFN1><<<dim3(M / 64, CFF / 128), blk, 24576, stream>>>(
        x_bf, w1T, bpack + 1792, h1_bf, M, CD, CFF);

    // FFN2 + bias + residual(x_bf bf16) + LN2 -> out fp32
    gemm_ln32<true, false, true><<<dim3(M / 16), blk, 0, stream>>>(
        h1_bf, w2T, bpack + 2816, x_bf, g2, be2, out, nullptr, CFF);
}

// Round 4
// 228.652 us; speedup vs baseline: 1.0193x; 1.0014x over previous
//
#include <hip/hip_runtime.h>
#include <hip/hip_bf16.h>
#include <cmath>

// Problem constants (fixed by the reference)
constexpr int CB  = 8;     // batch
constexpr int CN  = 1024;  // sequence length
constexpr int CD  = 256;   // model dim
constexpr int CH  = 8;     // heads
constexpr int CDH = 32;    // head dim
constexpr int CR  = 4;     // relation types (adj value 4 = none)
constexpr int CFF = 1024;  // ffn dim
constexpr float CEPS = 1e-5f;
constexpr float CS = 0.25503480f;   // (1/sqrt(32)) * log2(e), folded into Q
constexpr size_t SZH = (size_t)CB * CH * CN * CDH;  // 2M: one head-plane

#define MODE_QK    0   // scatter bf16 q/k head-major planes, +bias (cols 0..511)
#define MODE_FFN1  2   // +bias, tanh-gelu -> bf16
#define MODE_VT    4   // V^T gemm (A=weight rows, B=src rows): c-order column store

typedef float v4f __attribute__((ext_vector_type(4)));
typedef short v8s __attribute__((ext_vector_type(8)));

static __device__ __forceinline__ short f2bf(float f) {
    unsigned u = __builtin_bit_cast(unsigned, f);
    u += 0x7fff + ((u >> 16) & 1);          // round-to-nearest-even
    return (short)(u >> 16);
}
static __device__ __forceinline__ float bf2f(short s) {
    unsigned u = ((unsigned)(unsigned short)s) << 16;
    return __builtin_bit_cast(float, u);
}
static __device__ __forceinline__ unsigned cvtpk_bf16(float lo, float hi) {
    unsigned r;
    asm("v_cvt_pk_bf16_f32 %0, %1, %2" : "=v"(r) : "v"(lo), "v"(hi));
    return r;
}

static __device__ __forceinline__ void async_copy16(const void* g, void* l) {
    __builtin_amdgcn_global_load_lds(
        (const __attribute__((address_space(1))) void*)g,
        (__attribute__((address_space(3))) void*)l, 16, 0, 0);
}

// PV k-order permutation sigma(j): c[5]=j[4], c[4:3]=j[3:2], c[2]=j[5],
// c[1:0]=j[1:0].  With swapped QK^T (sacc = mfma(K,Q)), lane (quad,l15)
// holds P[i=l15][j=16jb+4quad+rr], and sigma maps those 16 j's exactly onto
// PV A-operand k-slots {kb*32 + quad*8 + e} -> P never touches LDS.

// ---------------------------------------------------------------------------
// bf16 MFMA GEMM body (device fn, dynamic LDS): epilogue(A[M,K] @ Bw[N,K])
// BM x BN tile, 4 waves 2x2, BK=32 double-buffered 1-deep prefetch.
// ---------------------------------------------------------------------------
template<int BM, int BN, int MODE>
__device__ __forceinline__ void gemm_body(
    const short* __restrict__ A, const short* __restrict__ Bw,
    const float* __restrict__ biasv, void* __restrict__ dest,
    int M, int K, int Nw, int bx, int by, short* smem)
{
    constexpr int WTM = BM / 2, WTN = BN / 2;
    constexpr int TM = WTM / 16, TN = WTN / 16;
    short* As = smem;                    // [2][BM*32]
    short* Bs = smem + 2 * BM * 32;      // [2][BN*32]

    const int t    = threadIdx.x;
    const int lane = t & 63;
    const int w    = t >> 6;
    const int quad = lane >> 4, l15 = lane & 15;
    const int wm = w >> 1, wn = w & 1;
    const int m0 = bx * BM, n0 = by * BN;

    const int srow = lane >> 2;
    const int scol = (lane & 3) * 8;

    v4f acc[TM][TN];
    #pragma unroll
    for (int i = 0; i < TM; ++i)
        #pragma unroll
        for (int j = 0; j < TN; ++j) acc[i][j] = (v4f){0.f, 0.f, 0.f, 0.f};

    const int NK = K >> 5;

    auto stage = [&](int buf, int kt) {
        #pragma unroll
        for (int u = 0; u < BM / 64; ++u) {
            const int e0 = (w * (BM / 64) + u) * 512;
            const int row = (e0 >> 5) + srow;
            async_copy16(A + (size_t)(m0 + row) * K + kt + scol,
                         &As[buf * BM * 32 + e0]);
        }
        #pragma unroll
        for (int u = 0; u < BN / 64; ++u) {
            const int e0 = (w * (BN / 64) + u) * 512;
            const int row = (e0 >> 5) + srow;
            async_copy16(Bw + (size_t)(n0 + row) * K + kt + scol,
                         &Bs[buf * BN * 32 + e0]);
        }
    };

    stage(0, 0);

    for (int it = 0; it < NK; ++it) {
        __syncthreads();
        if (it + 1 < NK) stage((it + 1) & 1, (it + 1) << 5);

        const int buf = it & 1;
        v8s af[TM], bfr[TN];
        #pragma unroll
        for (int i = 0; i < TM; ++i)
            af[i] = *(const v8s*)&As[buf * BM * 32 +
                                     (wm * WTM + i * 16 + l15) * 32 + quad * 8];
        #pragma unroll
        for (int j = 0; j < TN; ++j)
            bfr[j] = *(const v8s*)&Bs[buf * BN * 32 +
                                      (wn * WTN + j * 16 + l15) * 32 + quad * 8];
        #pragma unroll
        for (int i = 0; i < TM; ++i)
            #pragma unroll
            for (int j = 0; j < TN; ++j)
                acc[i][j] = __builtin_amdgcn_mfma_f32_16x16x32_bf16(
                    af[i], bfr[j], acc[i][j], 0, 0, 0);
    }

    #pragma unroll
    for (int i = 0; i < TM; ++i) {
        #pragma unroll
        for (int j = 0; j < TN; ++j) {
            const int mb = m0 + wm * WTM + i * 16 + quad * 4;   // row of rr=0
            const int n  = n0 + wn * WTN + j * 16 + l15;
            float vals[4];
            if (MODE == MODE_VT) {
                #pragma unroll
                for (int rr = 0; rr < 4; ++rr) vals[rr] = acc[i][j][rr] + biasv[mb + rr];
            } else {
                #pragma unroll
                for (int rr = 0; rr < 4; ++rr) vals[rr] = acc[i][j][rr] + biasv[n];
            }

            if (MODE == MODE_QK) {
                // fold softmax scale into Q (q-plane blocks have n0 < 256)
                if (n0 < 256) {
                    #pragma unroll
                    for (int rr = 0; rr < 4; ++rr) vals[rr] *= CS;
                }
                const int b = mb >> 10, ii0 = mb & 1023;
                const int plane = n >> 8, nn = n & 255;
                const int h = nn >> 5, d = nn & 31;
                #pragma unroll
                for (int rr = 0; rr < 4; ++rr)
                    ((short*)dest)[(size_t)plane * SZH +
                        (((size_t)(b * CH + h)) * CN + ii0 + rr) * CDH + d] =
                        f2bf(vals[rr]);
            } else if (MODE == MODE_VT) {
                // sigma column permutation within each 64-token tile (see top)
                const int b = n >> 10, ii = n & 1023;
                const int jj = ii & 63;
                const int cc = (((jj >> 4) & 1) << 5) | (((jj >> 2) & 3) << 3) |
                               (((jj >> 5) & 1) << 2) | (jj & 3);
                const int iip = (ii & ~63) | cc;
                #pragma unroll
                for (int rr = 0; rr < 4; ++rr) {
                    const int m = mb + rr;
                    const int r2 = m >> 8, hd = m & 255;
                    const int h = hd >> 5, d = hd & 31;
                    ((short*)dest)[2 * SZH +
                        (((size_t)(r2 * 64 + b * CH + h)) * CDH + d) * CN + iip] =
                        f2bf(vals[rr]);
                }
            } else { // MODE_FFN1: tanh-gelu -> bf16 (x*E/(E+1))
                #pragma unroll
                for (int rr = 0; rr < 4; ++rr) {
                    const size_t idx = (size_t)(mb + rr) * Nw + n;
                    const float xx = vals[rr];
                    const float E = exp2f(2.302217f * (xx + 0.044715f * xx * xx * xx));
                    ((short*)dest)[idx] = f2bf(xx * E / (E + 1.f));
                }
            }
        }
    }
}

template<int BM, int BN, int MODE>
__global__ __launch_bounds__(256)
void gemm_mfma(const short* __restrict__ A, const short* __restrict__ Bw,
               const float* __restrict__ biasv, void* __restrict__ dest,
               int M, int K, int Nw)
{
    extern __shared__ short smem[];
    gemm_body<BM, BN, MODE>(A, Bw, biasv, dest, M, K, Nw,
                            blockIdx.x, blockIdx.y, smem);
}

// ---------------------------------------------------------------------------
// Fused projection dispatch: blocks 0..511 = QK (8192x512), 512..1535 = V^T,
// 1536..2047 = adj int32 -> 4-BIT pack in sigma order.
// ---------------------------------------------------------------------------
__global__ __launch_bounds__(256)
void proj_kernel(const short* __restrict__ src_bf, const short* __restrict__ wqkvT,
                 const float* __restrict__ bpack, short* __restrict__ qkv,
                 const int* __restrict__ adj, unsigned char* __restrict__ adj4)
{
    extern __shared__ short smem[];
    const int g = blockIdx.x;
    if (g < 512) {
        gemm_body<64, 128, MODE_QK>(src_bf, wqkvT, bpack, qkv,
                                    8192, 256, 512, g >> 2, g & 3, smem);
    } else if (g < 1536) {
        const int h2 = g - 512;
        gemm_body<64, 128, MODE_VT>(wqkvT + 512 * 256, src_bf, bpack + 512,
                                    qkv, 1024, 256, 8192, h2 & 15, h2 >> 4, smem);
    } else {
        // sigma-order 4-bit pack: dword (row, dwi) covers c = (dwi&7)*8 + n
        // of tile T = dwi>>3.  sigma^-1 gives j = j0 + {0..3} and j0+32+{0..3}
        // with j0 = (kq&3)*4 + (kq>>2)*16  (kq = dwi&7)  -> two int4 loads.
        const int nout = CB * CN * CN / 8;           // 1M dwords
        for (int i = (g - 1536) * 256 + threadIdx.x; i < nout; i += 512 * 256) {
            const int dwi = i & 127;
            const int row = i >> 7;
            const int T   = dwi >> 3, kq = dwi & 7;
            const int j0  = T * 64 + (kq & 3) * 4 + (kq >> 2) * 16;
            const int* p = adj + (size_t)row * CN + j0;
            const int4 q0 = *(const int4*)(p);
            const int4 q1 = *(const int4*)(p + 32);
            const unsigned pk =
                (unsigned)(q0.x & 0xf)         | ((unsigned)(q0.y & 0xf) << 4)  |
                ((unsigned)(q0.z & 0xf) << 8)  | ((unsigned)(q0.w & 0xf) << 12) |
                ((unsigned)(q1.x & 0xf) << 16) | ((unsigned)(q1.y & 0xf) << 20) |
                ((unsigned)(q1.z & 0xf) << 24) | ((unsigned)(q1.w & 0xf) << 28);
            ((unsigned*)adj4)[i] = pk;
        }
    }
}

// ---------------------------------------------------------------------------
// FUSED GEMM + bias + residual + LayerNorm, BM=16 -> 512 blocks (2/CU).
// OUTF: write fp32 result; OUTB: write bf16 result; ADDBF: residual is bf16.
// ---------------------------------------------------------------------------
template<bool OUTF, bool OUTB, bool ADDBF>
__global__ __launch_bounds__(256)
void gemm_ln32(const short* __restrict__ A, const short* __restrict__ Bw,
               const float* __restrict__ biasv, const void* __restrict__ addp,
               const float* __restrict__ gw, const float* __restrict__ be,
               float* __restrict__ outf, short* __restrict__ outb, int K)
{
    __shared__ short As[2][16 * 32];
    __shared__ short Bs[2][256 * 32];
    __shared__ float redS[16][4], redQ[16][4];

    const int t    = threadIdx.x;
    const int lane = t & 63;
    const int w    = t >> 6;          // wave -> column quarter (64 cols)
    const int quad = lane >> 4, l15 = lane & 15;
    const int m0   = blockIdx.x * 16;

    const int srow = lane >> 2;
    const int scol = (lane & 3) * 8;

    v4f acc[4];
    #pragma unroll
    for (int j = 0; j < 4; ++j) acc[j] = (v4f){0.f, 0.f, 0.f, 0.f};

    const int NK = K >> 5;

    auto stage = [&](int buf, int kt) {
        if (t < 64)   // A: 16 rows, one DMA per lane of wave 0
            async_copy16(A + (size_t)(m0 + (t >> 2)) * K + kt + (t & 3) * 8,
                         &As[buf][t * 8]);
        #pragma unroll
        for (int u = 0; u < 4; ++u) {   // B: 256 rows, 4 DMAs/thread
            const int e0 = (w * 4 + u) * 512;
            async_copy16(Bw + (size_t)((e0 >> 5) + srow) * K + kt + scol,
                         &Bs[buf][e0]);
        }
    };

    stage(0, 0);

    for (int it = 0; it < NK; ++it) {
        __syncthreads();
        if (it + 1 < NK) stage((it + 1) & 1, (it + 1) << 5);

        const int buf = it & 1;
        const v8s af = *(const v8s*)&As[buf][l15 * 32 + quad * 8];
        #pragma unroll
        for (int j = 0; j < 4; ++j) {
            const v8s bfr = *(const v8s*)&Bs[buf][(w * 64 + 16 * j + l15) * 32 + quad * 8];
            acc[j] = __builtin_amdgcn_mfma_f32_16x16x32_bf16(af, bfr, acc[j], 0, 0, 0);
        }
    }

    float v[4][4];
    #pragma unroll
    for (int rr = 0; rr < 4; ++rr) {
        const int row = m0 + quad * 4 + rr;
        float s = 0.f, sq = 0.f;
        #pragma unroll
        for (int j = 0; j < 4; ++j) {
            const int n = w * 64 + 16 * j + l15;
            const size_t idx = (size_t)row * CD + n;
            const float addv = ADDBF ? bf2f(((const short*)addp)[idx])
                                     : ((const float*)addp)[idx];
            const float x = acc[j][rr] + biasv[n] + addv;
            v[rr][j] = x;
            s += x; sq += x * x;
        }
        #pragma unroll
        for (int off = 1; off < 16; off <<= 1) {
            s  += __shfl_xor(s, off);
            sq += __shfl_xor(sq, off);
        }
        if (l15 == 0) {
            redS[quad * 4 + rr][w] = s;
            redQ[quad * 4 + rr][w] = sq;
        }
    }
    __syncthreads();

    #pragma unroll
    for (int rr = 0; rr < 4; ++rr) {
        const int r16 = quad * 4 + rr;
        const int row = m0 + r16;
        const float s  = (redS[r16][0] + redS[r16][1]) + (redS[r16][2] + redS[r16][3]);
        const float sq = (redQ[r16][0] + redQ[r16][1]) + (redQ[r16][2] + redQ[r16][3]);
        const float mean = s * (1.f / CD);
        const float var  = sq * (1.f / CD) - mean * mean;
        const float rstd = rsqrtf(var + CEPS);
        #pragma unroll
        for (int j = 0; j < 4; ++j) {
            const int n = w * 64 + 16 * j + l15;
            const float y = (v[rr][j] - mean) * rstd * gw[n] + be[n];
            if (OUTF) outf[(size_t)row * CD + n] = y;
            if (OUTB) outb[(size_t)row * CD + n] = f2bf(y);
        }
    }
}

// ---------------------------------------------------------------------------
// Prep: src->bf16, weight transposes via 64x64 LDS tiles, biases packed.
// ---------------------------------------------------------------------------
__global__ __launch_bounds__(256)
void prep(const float* __restrict__ src,
          const float* __restrict__ Wq, const float* __restrict__ Wk,
          const float* __restrict__ Wv, const float* __restrict__ Wo,
          const float* __restrict__ W1, const float* __restrict__ W2,
          const float* __restrict__ bq, const float* __restrict__ bk,
          const float* __restrict__ bv, const float* __restrict__ bo,
          const float* __restrict__ b1, const float* __restrict__ b2,
          short* __restrict__ src_bf,
          short* __restrict__ wqkvT, short* __restrict__ woT,
          short* __restrict__ w1T, short* __restrict__ w2T,
          float* __restrict__ bpack)
{
    __shared__ float tile[64][65];
    const int bx = blockIdx.x, t = threadIdx.x;
    if (bx < 2048) {                                   // src cast: 512K float4
        const int i = bx * 256 + t;
        const float4 v = ((const float4*)src)[i];
        short4 o;
        o.x = f2bf(v.x); o.y = f2bf(v.y); o.z = f2bf(v.z); o.w = f2bf(v.w);
        ((short4*)src_bf)[i] = o;
    } else if (bx < 2288) {                            // weight transposes
        const int tt = bx - 2048;
        const float* S; short* D;
        int Sstride, Dstride, k0, srccol, dstrow;
        if (tt < 96) {                                 // wqkv: 24x4 tiles
            const int tk = tt & 3, tn = tt >> 2;
            const int ng = tn * 64;
            Sstride = 256; Dstride = 256; k0 = tk * 64;
            dstrow = tn * 64; D = wqkvT;
            if (ng < 256)      { S = Wq; srccol = ng; }
            else if (ng < 512) { S = Wk; srccol = ng - 256; }
            else { const int r = (ng - 512) >> 8;
                   S = Wv + (size_t)r * 65536; srccol = (ng - 512) & 255; }
        } else if (tt < 112) {                         // wo: 4x4
            const int u = tt - 96, tk = u & 3, tn = u >> 2;
            S = Wo; Sstride = 256; D = woT; Dstride = 256;
            k0 = tk * 64; srccol = tn * 64; dstrow = tn * 64;
        } else if (tt < 176) {                         // w1: 16x4
            const int u = tt - 112, tk = u & 3, tn = u >> 2;
            S = W1; Sstride = 1024; D = w1T; Dstride = 256;
            k0 = tk * 64; srccol = tn * 64; dstrow = tn * 64;
        } else {                                       // w2: 4x16
            const int u = tt - 176, tk = u & 15, tn = u >> 4;
            S = W2; Sstride = 256; D = w2T; Dstride = 1024;
            k0 = tk * 64; srccol = tn * 64; dstrow = tn * 64;
        }
        #pragma unroll
        for (int u2 = 0; u2 < 4; ++u2) {               // coalesced read
            const int kl = (t >> 4) + u2 * 16;
            const int nl = (t & 15) * 4;
            const float4 v = *(const float4*)&S[(size_t)(k0 + kl) * Sstride + srccol + nl];
            tile[kl][nl + 0] = v.x; tile[kl][nl + 1] = v.y;
            tile[kl][nl + 2] = v.z; tile[kl][nl + 3] = v.w;
        }
        __syncthreads();
        #pragma unroll
        for (int u2 = 0; u2 < 4; ++u2) {               // coalesced write
            const int nl = (t >> 4) + u2 * 16;
            const int kl = (t & 15) * 4;
            short4 o;
            o.x = f2bf(tile[kl + 0][nl]); o.y = f2bf(tile[kl + 1][nl]);
            o.z = f2bf(tile[kl + 2][nl]); o.w = f2bf(tile[kl + 3][nl]);
            *(short4*)&D[(size_t)(dstrow + nl) * Dstride + k0 + kl] = o;
        }
    } else {                                           // biases: 3072
        const int idx = (bx - 2288) * 256 + t;
        float bvv;
        if (idx < 256)       bvv = bq[idx];
        else if (idx < 512)  bvv = bk[idx - 256];
        else if (idx < 1536) bvv = bv[idx - 512];
        else if (idx < 1792) bvv = bo[idx - 1536];
        else if (idx < 2816) bvv = b1[idx - 1792];
        else                 bvv = b2[idx - 2816];
        bpack[idx] = bvv;
    }
}

// ---------------------------------------------------------------------------
// Fused relational attention, register-resident P (no P LDS at all):
//  - QK^T computed SWAPPED: sacc = mfma(K, Q) -> lane (quad,l15) holds
//    P[i=l15][j=16jb+4quad+rr]; sigma k-order makes these exactly the PV
//    A-operand k-slots, so exp+cvt_pk+mask feed PV MFMA straight from regs
//  - V^T staged by global_load_lds 2-deep ring (source-granule XOR swizzle)
//  - K and adj read direct from L2 into registers, prefetched 1 tile ahead
//  - softmax denominator is a lane-local accumulator (one reduce at end)
// One __syncthreads per j-tile.  XCD-aware 1D grid (b = g & 7).
// ---------------------------------------------------------------------------
__global__ __launch_bounds__(256, 4)
void attn_mfma(const short* __restrict__ qg, const short* __restrict__ kg,
               const short* __restrict__ vt, const unsigned char* __restrict__ adj4,
               short* __restrict__ outh)
{
    __shared__ __align__(16) short vtl[2][8192];  // [buf][r*2048 + d*64 + gc*8]

    const int t    = threadIdx.x;
    const int lane = t & 63;
    const int w    = t >> 6;          // wave 0..3
    const int quad = lane >> 4;
    const int l15  = lane & 15;
    const int g    = blockIdx.x;      // 1D grid, XCD-aware decode
    const int b    = g & 7;           // same XCD for whole batch
    const int h    = (g >> 3) & 7;
    const int i0   = (g >> 6) * 64;
    const int bhh  = b * CH + h;
    const size_t bh = (size_t)bhh;

    const v8s qfrag = *(const v8s*)&qg[(bh * CN + i0 + 16 * w + l15) * CDH + quad * 8];

    // V DMA sources: thread t stages granule gl = t + 256u; LDS granule
    // (r,d,gc) holds global granule gc^(d&7) of V^T row (r,d) in this j-tile.
    const short* vsrc[4];
    #pragma unroll
    for (int u = 0; u < 4; ++u) {
        const int gl = t + 256 * u;
        const int r = gl >> 8, d = (gl >> 3) & 31, gc = gl & 7;
        vsrc[u] = vt + ((size_t)(r * 64 + bhh) * CDH + d) * CN + (gc ^ (d & 7)) * 8;
    }
    // K direct: A-operand rows l15, k-chunk quad*8
    const short* kbase = kg + (bh * CN + l15) * CDH + quad * 8;
    // adj direct: row i0+16w+l15, dword (kb*4+quad) of the 32B tile slice
    const unsigned char* abase =
        adj4 + ((size_t)(b * CN) + i0 + 16 * w + l15) * (CN / 2) + quad * 4;

    v4f oacc[2];
    oacc[0] = (v4f){0.f, 0.f, 0.f, 0.f};
    oacc[1] = (v4f){0.f, 0.f, 0.f, 0.f};
    float plsum = 0.f;                     // lane-local: row i=l15, this quad's j's
    const int psw = (l15 & 7) * 8;         // vfrag granule XOR (pre-scaled)

    // ---- prologue: prefetch tile 0 ----
    #pragma unroll
    for (int u = 0; u < 4; ++u)
        async_copy16(vsrc[u], &vtl[0][(t + 256 * u) * 8]);
    v8s kpre[4];
    #pragma unroll
    for (int jb = 0; jb < 4; ++jb)
        kpre[jb] = *(const v8s*)(kbase + (16 * jb) * CDH);
    unsigned apre0 = *(const unsigned*)(abase);
    unsigned apre1 = *(const unsigned*)(abase + 16);

    for (int jt = 0; jt < 16; ++jt) {
        __syncthreads();   // vtl[jt&1] staged; other buf free for prefetch
        const int p = jt & 1;

        // ---- QK swapped: sacc[jb] row=j-local, col=i-local ----
        v4f sacc[4];
        #pragma unroll
        for (int jb = 0; jb < 4; ++jb)
            sacc[jb] = __builtin_amdgcn_mfma_f32_16x16x32_bf16(
                kpre[jb], qfrag, (v4f){0.f, 0.f, 0.f, 0.f}, 0, 0, 0);

        // ---- issue prefetches for tile jt+1 (wrap harmless on last iter) ----
        const unsigned a0 = apre0, a1 = apre1;
        const int jn = (jt + 1) & 15;
        #pragma unroll
        for (int u = 0; u < 4; ++u)
            async_copy16(vsrc[u] + jn * 64, &vtl[p ^ 1][(t + 256 * u) * 8]);
        #pragma unroll
        for (int jb = 0; jb < 4; ++jb)
            kpre[jb] = *(const v8s*)(kbase + (jn * 64 + 16 * jb) * CDH);
        apre0 = *(const unsigned*)(abase + jn * 32);
        apre1 = *(const unsigned*)(abase + jn * 32 + 16);

        // ---- softmax numerators, all in registers ----
        float pv[4][4];   // [jb][rr] = P[i=l15][j=16jb+4quad+rr]
        #pragma unroll
        for (int jb = 0; jb < 4; ++jb)
            #pragma unroll
            for (int rr = 0; rr < 4; ++rr) pv[jb][rr] = exp2f(sacc[jb][rr]);
        plsum += ((pv[0][0] + pv[0][1]) + (pv[0][2] + pv[0][3]))
               + ((pv[1][0] + pv[1][1]) + (pv[1][2] + pv[1][3]))
               + ((pv[2][0] + pv[2][1]) + (pv[2][2] + pv[2][3]))
               + ((pv[3][0] + pv[3][1]) + (pv[3][2] + pv[3][3]));

        // ---- PV: pack P pairs, mask per relation, MFMA from registers ----
        #pragma unroll
        for (int kb = 0; kb < 2; ++kb) {
            // A-operand dwords: e = {0..7} = rr of jb=kb then rr of jb=kb+2
            const unsigned P[4] = {
                cvtpk_bf16(pv[kb][0],     pv[kb][1]),
                cvtpk_bf16(pv[kb][2],     pv[kb][3]),
                cvtpk_bf16(pv[kb + 2][0], pv[kb + 2][1]),
                cvtpk_bf16(pv[kb + 2][2], pv[kb + 2][3])};
            const unsigned ab32 = kb ? a1 : a0;
            unsigned pf[4][4];
            #pragma unroll
            for (int u = 0; u < 4; ++u) {
                // splat byte u into both halves, isolate (v0 | v1<<4 in hi)
                const unsigned sel = 0x0c000c00u | (unsigned)u | ((unsigned)u << 16);
                const unsigned a2 = __builtin_amdgcn_perm(ab32, ab32, sel) & 0x00F0000Fu;
                #pragma unroll
                for (int r = 0; r < 4; ++r) {
                    const unsigned x = a2 ^ ((unsigned)r | ((unsigned)r << 20));
                    unsigned tt, mm;
                    // per-half: (half==0) -> 0xffff else 0
                    asm("v_pk_add_i16 %0, %1, %2"
                        : "=v"(tt) : "v"(x), "v"(0xffffffffu));
                    asm("v_pk_ashrrev_i16 %0, %1, %2"
                        : "=v"(mm) : "v"(0x000f000fu), "v"(tt));
                    pf[r][u] = P[u] & mm;
                }
            }
            #pragma unroll
            for (int r = 0; r < 4; ++r) {
                const v8s pfr = __builtin_bit_cast(v8s,
                    make_uint4(pf[r][0], pf[r][1], pf[r][2], pf[r][3]));
                #pragma unroll
                for (int cb = 0; cb < 2; ++cb) {
                    const v8s vfrag = *(const v8s*)&vtl[p][r * 2048 +
                        (16 * cb + l15) * 64 + (((4 * kb + quad) * 8) ^ psw)];
                    oacc[cb] = __builtin_amdgcn_mfma_f32_16x16x32_bf16(
                        pfr, vfrag, oacc[cb], 0, 0, 0);
                }
            }
        }
    }

    // ---- epilogue: reduce plsum over quads, redistribute, normalize ----
    float plF = plsum;
    plF += __shfl_xor(plF, 16);
    plF += __shfl_xor(plF, 32);            // lane x: denom for row i=x&15
    #pragma unroll
    for (int rr = 0; rr < 4; ++rr) {
        const float inv = 1.f / __shfl(plF, quad * 4 + rr);
        const int row = i0 + 16 * w + quad * 4 + rr;
        #pragma unroll
        for (int cb = 0; cb < 2; ++cb)
            outh[((size_t)b * CN + row) * CD + h * CDH + 16 * cb + l15] =
                f2bf(oacc[cb][rr] * inv);
    }
}

// ---------------------------------------------------------------------------
extern "C" void kernel_launch(void* const* d_in, const int* in_sizes, int n_in,
                              void* d_out, int out_size, void* d_ws, size_t ws_size,
                              hipStream_t stream)
{
    const float* src = (const float*)d_in[0];
    const int*   adj = (const int*)d_in[1];
    const float* Wq  = (const float*)d_in[2];
    const float* bq  = (const float*)d_in[3];
    const float* Wk  = (const float*)d_in[4];
    const float* bk  = (const float*)d_in[5];
    const float* Wv  = (const float*)d_in[6];
    const float* bv  = (const float*)d_in[7];
    const float* Wo  = (const float*)d_in[8];
    const float* bo  = (const float*)d_in[9];
    const float* W1  = (const float*)d_in[10];
    const float* b1  = (const float*)d_in[11];
    const float* W2  = (const float*)d_in[12];
    const float* b2  = (const float*)d_in[13];
    const float* g1  = (const float*)d_in[14];
    const float* be1 = (const float*)d_in[15];
    const float* g2  = (const float*)d_in[16];
    const float* be2 = (const float*)d_in[17];
    float* out = (float*)d_out;

    char* wsb = (char*)d_ws;
    const size_t MB = (size_t)1 << 20;

    // workspace layout (42 MB with aliasing)
    unsigned char* adj4 = (unsigned char*)(wsb);            // [0,4) MB packed adj
    short* qkv_bf = (short*)(wsb + 8 * MB);                 // [8,32): q,k planes + vT
    short* src_bf = (short*)(wsb + 32 * MB);                // [32,36)
    short* wqkvT  = (short*)(wsb + 36 * MB);                // 768 KB
    short* woT    = (short*)(wsb + 36 * MB + 768 * 1024);   // 128 KB
    short* w1T    = (short*)(wsb + 36 * MB + 896 * 1024);   // 512 KB
    short* w2T    = (short*)(wsb + 36 * MB + 1408 * 1024);  // 512 KB
    float* bpack  = (float*)(wsb + 36 * MB + 1920 * 1024);  // 12 KB
    short* heads_bf = (short*)(wsb + 38 * MB);              // [38,42)
    short* x_bf   = (short*)(wsb + 32 * MB);                // reuse src_bf (LN1 out)
    short* h1_bf  = (short*)(wsb + 16 * MB);                // reuse vT (dead post-attn)

    const int M = CB * CN;        // 8192
    dim3 blk(256);

    // prep: src cast, coalesced weight transposes, biases (2300 blocks)
    prep<<<dim3(2300), blk, 0, stream>>>(src, Wq, Wk, Wv, Wo, W1, W2,
        bq, bk, bv, bo, b1, b2, src_bf, wqkvT, woT, w1T, w2T, bpack);

    // fused QK + V^T projection + sigma-order 4-bit adj pack: 2048 blocks
    proj_kernel<<<dim3(2048), blk, 24576, stream>>>(
        src_bf, wqkvT, bpack, qkv_bf, adj, adj4);

    // fused relational MFMA attention (XCD-aware 1D grid) -> bf16 heads
    attn_mfma<<<dim3(1024), blk, 0, stream>>>(
        qkv_bf, qkv_bf + SZH, qkv_bf + 2 * SZH, adj4, heads_bf);

    // O-projection + bias + residual(src fp32) + LN1 -> x_bf bf16 only
    gemm_ln32<false, true, false><<<dim3(M / 16), blk, 0, stream>>>(
        heads_bf, woT, bpack + 1536, src, g1, be1, nullptr, x_bf, CD);

    // FFN1: 1024 blocks
    gemm_mfma<64, 128, MODE_FFN1><<<dim3(M / 64, CFF / 128), blk, 24576, stream>>>(
        x_bf, w1T, bpack + 1792, h1_bf, M, CD, CFF);

    // FFN2 + bias + residual(x_bf bf16) + LN2 -> out fp32
    gemm_ln32<true, false, true><<<dim3(M / 16), blk, 0, stream>>>(
        h1_bf, w2T, bpack + 2816, x_bf, g2, be2, out, nullptr, CFF);
}

// Round 5
// 225.602 us; speedup vs baseline: 1.0331x; 1.0135x over previous
//
#include <hip/hip_runtime.h>
#include <hip/hip_bf16.h>
#include <cmath>

// Problem constants (fixed by the reference)
constexpr int CB  = 8;     // batch
constexpr int CN  = 1024;  // sequence length
constexpr int CD  = 256;   // model dim
constexpr int CH  = 8;     // heads
constexpr int CDH = 32;    // head dim
constexpr int CR  = 4;     // relation types (adj value 4 = none)
constexpr int CFF = 1024;  // ffn dim
constexpr float CEPS = 1e-5f;
constexpr float CS = 0.25503480f;   // (1/sqrt(32)) * log2(e), folded into Q
constexpr size_t SZH = (size_t)CB * CH * CN * CDH;  // 2M: one head-plane

#define MODE_QK    0   // scatter bf16 q/k head-major planes, +bias (cols 0..511)
#define MODE_FFN1  2   // +bias, tanh-gelu -> bf16
#define MODE_VT    4   // V^T gemm (A=weight rows, B=src rows): sigma column store

typedef float v4f __attribute__((ext_vector_type(4)));
typedef short v8s __attribute__((ext_vector_type(8)));

static __device__ __forceinline__ short f2bf(float f) {
    unsigned u = __builtin_bit_cast(unsigned, f);
    u += 0x7fff + ((u >> 16) & 1);          // round-to-nearest-even
    return (short)(u >> 16);
}
static __device__ __forceinline__ float bf2f(short s) {
    unsigned u = ((unsigned)(unsigned short)s) << 16;
    return __builtin_bit_cast(float, u);
}
static __device__ __forceinline__ unsigned cvtpk_bf16(float lo, float hi) {
    unsigned r;
    asm("v_cvt_pk_bf16_f32 %0, %1, %2" : "=v"(r) : "v"(lo), "v"(hi));
    return r;
}

static __device__ __forceinline__ void async_copy16(const void* g, void* l) {
    __builtin_amdgcn_global_load_lds(
        (const __attribute__((address_space(1))) void*)g,
        (__attribute__((address_space(3))) void*)l, 16, 0, 0);
}

// PV k-order permutation sigma(j): c[5]=j[4], c[4:3]=j[3:2], c[2]=j[5],
// c[1:0]=j[1:0].  With swapped QK^T (sacc = mfma(K,Q)), lane (quad,l15)
// holds P[i=l15][j=16jb+4quad+rr], and sigma maps those 16 j's exactly onto
// PV A-operand k-slots {kb*32 + quad*8 + e} -> P never touches LDS.
// adjsel stores adj as BYTES in sigma pair order; at PV time the byte value
// itself is a v_perm selector into a one-hot 0xff table (v=4 -> zero operand).

// ---------------------------------------------------------------------------
// bf16 MFMA GEMM body (device fn, dynamic LDS): epilogue(A[M,K] @ Bw[N,K])
// BM x BN tile, 4 waves 2x2, BK=32 double-buffered 1-deep prefetch.
// ---------------------------------------------------------------------------
template<int BM, int BN, int MODE>
__device__ __forceinline__ void gemm_body(
    const short* __restrict__ A, const short* __restrict__ Bw,
    const float* __restrict__ biasv, void* __restrict__ dest,
    int M, int K, int Nw, int bx, int by, short* smem)
{
    constexpr int WTM = BM / 2, WTN = BN / 2;
    constexpr int TM = WTM / 16, TN = WTN / 16;
    short* As = smem;                    // [2][BM*32]
    short* Bs = smem + 2 * BM * 32;      // [2][BN*32]

    const int t    = threadIdx.x;
    const int lane = t & 63;
    const int w    = t >> 6;
    const int quad = lane >> 4, l15 = lane & 15;
    const int wm = w >> 1, wn = w & 1;
    const int m0 = bx * BM, n0 = by * BN;

    const int srow = lane >> 2;
    const int scol = (lane & 3) * 8;

    v4f acc[TM][TN];
    #pragma unroll
    for (int i = 0; i < TM; ++i)
        #pragma unroll
        for (int j = 0; j < TN; ++j) acc[i][j] = (v4f){0.f, 0.f, 0.f, 0.f};

    const int NK = K >> 5;

    auto stage = [&](int buf, int kt) {
        #pragma unroll
        for (int u = 0; u < BM / 64; ++u) {
            const int e0 = (w * (BM / 64) + u) * 512;
            const int row = (e0 >> 5) + srow;
            async_copy16(A + (size_t)(m0 + row) * K + kt + scol,
                         &As[buf * BM * 32 + e0]);
        }
        #pragma unroll
        for (int u = 0; u < BN / 64; ++u) {
            const int e0 = (w * (BN / 64) + u) * 512;
            const int row = (e0 >> 5) + srow;
            async_copy16(Bw + (size_t)(n0 + row) * K + kt + scol,
                         &Bs[buf * BN * 32 + e0]);
        }
    };

    stage(0, 0);

    for (int it = 0; it < NK; ++it) {
        __syncthreads();
        if (it + 1 < NK) stage((it + 1) & 1, (it + 1) << 5);

        const int buf = it & 1;
        v8s af[TM], bfr[TN];
        #pragma unroll
        for (int i = 0; i < TM; ++i)
            af[i] = *(const v8s*)&As[buf * BM * 32 +
                                     (wm * WTM + i * 16 + l15) * 32 + quad * 8];
        #pragma unroll
        for (int j = 0; j < TN; ++j)
            bfr[j] = *(const v8s*)&Bs[buf * BN * 32 +
                                      (wn * WTN + j * 16 + l15) * 32 + quad * 8];
        #pragma unroll
        for (int i = 0; i < TM; ++i)
            #pragma unroll
            for (int j = 0; j < TN; ++j)
                acc[i][j] = __builtin_amdgcn_mfma_f32_16x16x32_bf16(
                    af[i], bfr[j], acc[i][j], 0, 0, 0);
    }

    #pragma unroll
    for (int i = 0; i < TM; ++i) {
        #pragma unroll
        for (int j = 0; j < TN; ++j) {
            const int mb = m0 + wm * WTM + i * 16 + quad * 4;   // row of rr=0
            const int n  = n0 + wn * WTN + j * 16 + l15;
            float vals[4];
            if (MODE == MODE_VT) {
                #pragma unroll
                for (int rr = 0; rr < 4; ++rr) vals[rr] = acc[i][j][rr] + biasv[mb + rr];
            } else {
                #pragma unroll
                for (int rr = 0; rr < 4; ++rr) vals[rr] = acc[i][j][rr] + biasv[n];
            }

            if (MODE == MODE_QK) {
                // fold softmax scale into Q (q-plane blocks have n0 < 256)
                if (n0 < 256) {
                    #pragma unroll
                    for (int rr = 0; rr < 4; ++rr) vals[rr] *= CS;
                }
                const int b = mb >> 10, ii0 = mb & 1023;
                const int plane = n >> 8, nn = n & 255;
                const int h = nn >> 5, d = nn & 31;
                #pragma unroll
                for (int rr = 0; rr < 4; ++rr)
                    ((short*)dest)[(size_t)plane * SZH +
                        (((size_t)(b * CH + h)) * CN + ii0 + rr) * CDH + d] =
                        f2bf(vals[rr]);
            } else if (MODE == MODE_VT) {
                // sigma column permutation within each 64-token tile (see top)
                const int b = n >> 10, ii = n & 1023;
                const int jj = ii & 63;
                const int cc = (((jj >> 4) & 1) << 5) | (((jj >> 2) & 3) << 3) |
                               (((jj >> 5) & 1) << 2) | (jj & 3);
                const int iip = (ii & ~63) | cc;
                #pragma unroll
                for (int rr = 0; rr < 4; ++rr) {
                    const int m = mb + rr;
                    const int r2 = m >> 8, hd = m & 255;
                    const int h = hd >> 5, d = hd & 31;
                    ((short*)dest)[2 * SZH +
                        (((size_t)(r2 * 64 + b * CH + h)) * CDH + d) * CN + iip] =
                        f2bf(vals[rr]);
                }
            } else { // MODE_FFN1: tanh-gelu -> bf16 (x*E/(E+1))
                #pragma unroll
                for (int rr = 0; rr < 4; ++rr) {
                    const size_t idx = (size_t)(mb + rr) * Nw + n;
                    const float xx = vals[rr];
                    const float E = exp2f(2.302217f * (xx + 0.044715f * xx * xx * xx));
                    ((short*)dest)[idx] = f2bf(xx * E / (E + 1.f));
                }
            }
        }
    }
}

template<int BM, int BN, int MODE>
__global__ __launch_bounds__(256)
void gemm_mfma(const short* __restrict__ A, const short* __restrict__ Bw,
               const float* __restrict__ biasv, void* __restrict__ dest,
               int M, int K, int Nw)
{
    extern __shared__ short smem[];
    gemm_body<BM, BN, MODE>(A, Bw, biasv, dest, M, K, Nw,
                            blockIdx.x, blockIdx.y, smem);
}

// ---------------------------------------------------------------------------
// Fused projection dispatch (128x128 m97-style tiles):
//   blocks 0..255   = QK  (8192x512, K=256)
//   blocks 256..767 = V^T (1024x8192, K=256)
//   blocks 768..1279= adj int32 -> BYTE-pair pack in sigma order (adjsel)
// ---------------------------------------------------------------------------
__global__ __launch_bounds__(256)
void proj_kernel(const short* __restrict__ src_bf, const short* __restrict__ wqkvT,
                 const float* __restrict__ bpack, short* __restrict__ qkv,
                 const int* __restrict__ adj, unsigned char* __restrict__ adjsel)
{
    extern __shared__ short smem[];
    const int g = blockIdx.x;
    if (g < 256) {
        gemm_body<128, 128, MODE_QK>(src_bf, wqkvT, bpack, qkv,
                                     8192, 256, 512, g >> 2, g & 3, smem);
    } else if (g < 768) {
        const int h2 = g - 256;
        gemm_body<128, 128, MODE_VT>(wqkvT + 512 * 256, src_bf, bpack + 512,
                                     qkv, 1024, 256, 8192, h2 & 7, h2 >> 3, smem);
    } else {
        // sigma-order byte pack: int2 (row, dwi) holds adj bytes for the 8 j's
        // j0+{0..3}, j0+32+{0..3} with j0 = T*64 + (kq&3)*4 + (kq>>2)*16,
        // T = dwi>>3, kq = dwi&7  (kq = kb*4 + quad).
        const int nout = CB * CN * CN / 8;           // 1M int2 (8 j's each)
        for (int i = (g - 768) * 256 + threadIdx.x; i < nout; i += 512 * 256) {
            const int dwi = i & 127;
            const int row = i >> 7;
            const int T   = dwi >> 3, kq = dwi & 7;
            const int j0  = T * 64 + (kq & 3) * 4 + (kq >> 2) * 16;
            const int* p = adj + (size_t)row * CN + j0;
            const int4 q0 = *(const int4*)(p);
            const int4 q1 = *(const int4*)(p + 32);
            int2 o;
            o.x = (q0.x & 0xff) | ((q0.y & 0xff) << 8) |
                  ((q0.z & 0xff) << 16) | ((q0.w & 0xff) << 24);
            o.y = (q1.x & 0xff) | ((q1.y & 0xff) << 8) |
                  ((q1.z & 0xff) << 16) | ((q1.w & 0xff) << 24);
            ((int2*)adjsel)[i] = o;
        }
    }
}

// ---------------------------------------------------------------------------
// FUSED GEMM + bias + residual + LayerNorm, BM=16 -> 512 blocks (2/CU).
// OUTF: write fp32 result; OUTB: write bf16 result; ADDBF: residual is bf16.
// ---------------------------------------------------------------------------
template<bool OUTF, bool OUTB, bool ADDBF>
__global__ __launch_bounds__(256)
void gemm_ln32(const short* __restrict__ A, const short* __restrict__ Bw,
               const float* __restrict__ biasv, const void* __restrict__ addp,
               const float* __restrict__ gw, const float* __restrict__ be,
               float* __restrict__ outf, short* __restrict__ outb, int K)
{
    __shared__ short As[2][16 * 32];
    __shared__ short Bs[2][256 * 32];
    __shared__ float redS[16][4], redQ[16][4];

    const int t    = threadIdx.x;
    const int lane = t & 63;
    const int w    = t >> 6;          // wave -> column quarter (64 cols)
    const int quad = lane >> 4, l15 = lane & 15;
    const int m0   = blockIdx.x * 16;

    const int srow = lane >> 2;
    const int scol = (lane & 3) * 8;

    v4f acc[4];
    #pragma unroll
    for (int j = 0; j < 4; ++j) acc[j] = (v4f){0.f, 0.f, 0.f, 0.f};

    const int NK = K >> 5;

    auto stage = [&](int buf, int kt) {
        if (t < 64)   // A: 16 rows, one DMA per lane of wave 0
            async_copy16(A + (size_t)(m0 + (t >> 2)) * K + kt + (t & 3) * 8,
                         &As[buf][t * 8]);
        #pragma unroll
        for (int u = 0; u < 4; ++u) {   // B: 256 rows, 4 DMAs/thread
            const int e0 = (w * 4 + u) * 512;
            async_copy16(Bw + (size_t)((e0 >> 5) + srow) * K + kt + scol,
                         &Bs[buf][e0]);
        }
    };

    stage(0, 0);

    for (int it = 0; it < NK; ++it) {
        __syncthreads();
        if (it + 1 < NK) stage((it + 1) & 1, (it + 1) << 5);

        const int buf = it & 1;
        const v8s af = *(const v8s*)&As[buf][l15 * 32 + quad * 8];
        #pragma unroll
        for (int j = 0; j < 4; ++j) {
            const v8s bfr = *(const v8s*)&Bs[buf][(w * 64 + 16 * j + l15) * 32 + quad * 8];
            acc[j] = __builtin_amdgcn_mfma_f32_16x16x32_bf16(af, bfr, acc[j], 0, 0, 0);
        }
    }

    float v[4][4];
    #pragma unroll
    for (int rr = 0; rr < 4; ++rr) {
        const int row = m0 + quad * 4 + rr;
        float s = 0.f, sq = 0.f;
        #pragma unroll
        for (int j = 0; j < 4; ++j) {
            const int n = w * 64 + 16 * j + l15;
            const size_t idx = (size_t)row * CD + n;
            const float addv = ADDBF ? bf2f(((const short*)addp)[idx])
                                     : ((const float*)addp)[idx];
            const float x = acc[j][rr] + biasv[n] + addv;
            v[rr][j] = x;
            s += x; sq += x * x;
        }
        #pragma unroll
        for (int off = 1; off < 16; off <<= 1) {
            s  += __shfl_xor(s, off);
            sq += __shfl_xor(sq, off);
        }
        if (l15 == 0) {
            redS[quad * 4 + rr][w] = s;
            redQ[quad * 4 + rr][w] = sq;
        }
    }
    __syncthreads();

    #pragma unroll
    for (int rr = 0; rr < 4; ++rr) {
        const int r16 = quad * 4 + rr;
        const int row = m0 + r16;
        const float s  = (redS[r16][0] + redS[r16][1]) + (redS[r16][2] + redS[r16][3]);
        const float sq = (redQ[r16][0] + redQ[r16][1]) + (redQ[r16][2] + redQ[r16][3]);
        const float mean = s * (1.f / CD);
        const float var  = sq * (1.f / CD) - mean * mean;
        const float rstd = rsqrtf(var + CEPS);
        #pragma unroll
        for (int j = 0; j < 4; ++j) {
            const int n = w * 64 + 16 * j + l15;
            const float y = (v[rr][j] - mean) * rstd * gw[n] + be[n];
            if (OUTF) outf[(size_t)row * CD + n] = y;
            if (OUTB) outb[(size_t)row * CD + n] = f2bf(y);
        }
    }
}

// ---------------------------------------------------------------------------
// Prep: src->bf16, weight transposes via 64x64 LDS tiles, biases packed.
// ---------------------------------------------------------------------------
__global__ __launch_bounds__(256)
void prep(const float* __restrict__ src,
          const float* __restrict__ Wq, const float* __restrict__ Wk,
          const float* __restrict__ Wv, const float* __restrict__ Wo,
          const float* __restrict__ W1, const float* __restrict__ W2,
          const float* __restrict__ bq, const float* __restrict__ bk,
          const float* __restrict__ bv, const float* __restrict__ bo,
          const float* __restrict__ b1, const float* __restrict__ b2,
          short* __restrict__ src_bf,
          short* __restrict__ wqkvT, short* __restrict__ woT,
          short* __restrict__ w1T, short* __restrict__ w2T,
          float* __restrict__ bpack)
{
    __shared__ float tile[64][65];
    const int bx = blockIdx.x, t = threadIdx.x;
    if (bx < 2048) {                                   // src cast: 512K float4
        const int i = bx * 256 + t;
        const float4 v = ((const float4*)src)[i];
        short4 o;
        o.x = f2bf(v.x); o.y = f2bf(v.y); o.z = f2bf(v.z); o.w = f2bf(v.w);
        ((short4*)src_bf)[i] = o;
    } else if (bx < 2288) {                            // weight transposes
        const int tt = bx - 2048;
        const float* S; short* D;
        int Sstride, Dstride, k0, srccol, dstrow;
        if (tt < 96) {                                 // wqkv: 24x4 tiles
            const int tk = tt & 3, tn = tt >> 2;
            const int ng = tn * 64;
            Sstride = 256; Dstride = 256; k0 = tk * 64;
            dstrow = tn * 64; D = wqkvT;
            if (ng < 256)      { S = Wq; srccol = ng; }
            else if (ng < 512) { S = Wk; srccol = ng - 256; }
            else { const int r = (ng - 512) >> 8;
                   S = Wv + (size_t)r * 65536; srccol = (ng - 512) & 255; }
        } else if (tt < 112) {                         // wo: 4x4
            const int u = tt - 96, tk = u & 3, tn = u >> 2;
            S = Wo; Sstride = 256; D = woT; Dstride = 256;
            k0 = tk * 64; srccol = tn * 64; dstrow = tn * 64;
        } else if (tt < 176) {                         // w1: 16x4
            const int u = tt - 112, tk = u & 3, tn = u >> 2;
            S = W1; Sstride = 1024; D = w1T; Dstride = 256;
            k0 = tk * 64; srccol = tn * 64; dstrow = tn * 64;
        } else {                                       // w2: 4x16
            const int u = tt - 176, tk = u & 15, tn = u >> 4;
            S = W2; Sstride = 256; D = w2T; Dstride = 1024;
            k0 = tk * 64; srccol = tn * 64; dstrow = tn * 64;
        }
        #pragma unroll
        for (int u2 = 0; u2 < 4; ++u2) {               // coalesced read
            const int kl = (t >> 4) + u2 * 16;
            const int nl = (t & 15) * 4;
            const float4 v = *(const float4*)&S[(size_t)(k0 + kl) * Sstride + srccol + nl];
            tile[kl][nl + 0] = v.x; tile[kl][nl + 1] = v.y;
            tile[kl][nl + 2] = v.z; tile[kl][nl + 3] = v.w;
        }
        __syncthreads();
        #pragma unroll
        for (int u2 = 0; u2 < 4; ++u2) {               // coalesced write
            const int nl = (t >> 4) + u2 * 16;
            const int kl = (t & 15) * 4;
            short4 o;
            o.x = f2bf(tile[kl + 0][nl]); o.y = f2bf(tile[kl + 1][nl]);
            o.z = f2bf(tile[kl + 2][nl]); o.w = f2bf(tile[kl + 3][nl]);
            *(short4*)&D[(size_t)(dstrow + nl) * Dstride + k0 + kl] = o;
        }
    } else {                                           // biases: 3072
        const int idx = (bx - 2288) * 256 + t;
        float bvv;
        if (idx < 256)       bvv = bq[idx];
        else if (idx < 512)  bvv = bk[idx - 256];
        else if (idx < 1536) bvv = bv[idx - 512];
        else if (idx < 1792) bvv = bo[idx - 1536];
        else if (idx < 2816) bvv = b1[idx - 1792];
        else                 bvv = b2[idx - 2816];
        bpack[idx] = bvv;
    }
}

// ---------------------------------------------------------------------------
// Fused relational attention, register-resident P + byte-LUT masks:
//  - QK^T swapped (sacc = mfma(K,Q)) -> P lane-local; sigma k-order feeds PV
//  - adj bytes ARE v_perm selectors: D=[v0,v0,v1,v1] (1 perm), mask_r =
//    perm(0, 0xff<<8r, D) (1 perm + 1 and) -> 40 mask ops/jt (was 144)
//  - V^T staged by global_load_lds 2-deep ring (source-granule XOR swizzle)
//  - K and adjsel read direct from L2 into registers, prefetched 1 tile ahead
// One __syncthreads per j-tile.  XCD-aware 1D grid (b = g & 7).
// ---------------------------------------------------------------------------
__global__ __launch_bounds__(256, 4)
void attn_mfma(const short* __restrict__ qg, const short* __restrict__ kg,
               const short* __restrict__ vt, const unsigned char* __restrict__ adjsel,
               short* __restrict__ outh)
{
    __shared__ __align__(16) short vtl[2][8192];  // [buf][r*2048 + d*64 + gc*8]

    const int t    = threadIdx.x;
    const int lane = t & 63;
    const int w    = t >> 6;          // wave 0..3
    const int quad = lane >> 4;
    const int l15  = lane & 15;
    const int g    = blockIdx.x;      // 1D grid, XCD-aware decode
    const int b    = g & 7;           // same XCD for whole batch
    const int h    = (g >> 3) & 7;
    const int i0   = (g >> 6) * 64;
    const int bhh  = b * CH + h;
    const size_t bh = (size_t)bhh;

    const v8s qfrag = *(const v8s*)&qg[(bh * CN + i0 + 16 * w + l15) * CDH + quad * 8];

    // V DMA sources: thread t stages granule gl = t + 256u; LDS granule
    // (r,d,gc) holds global granule gc^(d&7) of V^T row (r,d) in this j-tile.
    const short* vsrc[4];
    #pragma unroll
    for (int u = 0; u < 4; ++u) {
        const int gl = t + 256 * u;
        const int r = gl >> 8, d = (gl >> 3) & 31, gc = gl & 7;
        vsrc[u] = vt + ((size_t)(r * 64 + bhh) * CDH + d) * CN + (gc ^ (d & 7)) * 8;
    }
    // K direct: A-operand rows l15, k-chunk quad*8
    const short* kbase = kg + (bh * CN + l15) * CDH + quad * 8;
    // adjsel direct: row i0+16w+l15, int2 (kb, quad) of the 64B tile slice
    const unsigned char* abase =
        adjsel + ((size_t)(b * CN) + i0 + 16 * w + l15) * CN + quad * 8;

    v4f oacc[2];
    oacc[0] = (v4f){0.f, 0.f, 0.f, 0.f};
    oacc[1] = (v4f){0.f, 0.f, 0.f, 0.f};
    float plsum = 0.f;                     // lane-local: row i=l15, this quad's j's
    const int psw = (l15 & 7) * 8;         // vfrag granule XOR (pre-scaled)

    // ---- prologue: prefetch tile 0 ----
    #pragma unroll
    for (int u = 0; u < 4; ++u)
        async_copy16(vsrc[u], &vtl[0][(t + 256 * u) * 8]);
    v8s kpre[4];
    #pragma unroll
    for (int jb = 0; jb < 4; ++jb)
        kpre[jb] = *(const v8s*)(kbase + (16 * jb) * CDH);
    int2 apre0 = *(const int2*)(abase);
    int2 apre1 = *(const int2*)(abase + 32);

    for (int jt = 0; jt < 16; ++jt) {
        __syncthreads();   // vtl[jt&1] staged; other buf free for prefetch
        const int p = jt & 1;

        // ---- QK swapped: sacc[jb] row=j-local, col=i-local ----
        v4f sacc[4];
        #pragma unroll
        for (int jb = 0; jb < 4; ++jb)
            sacc[jb] = __builtin_amdgcn_mfma_f32_16x16x32_bf16(
                kpre[jb], qfrag, (v4f){0.f, 0.f, 0.f, 0.f}, 0, 0, 0);

        // ---- issue prefetches for tile jt+1 (wrap harmless on last iter) ----
        const int2 a0 = apre0, a1 = apre1;
        const int jn = (jt + 1) & 15;
        #pragma unroll
        for (int u = 0; u < 4; ++u)
            async_copy16(vsrc[u] + jn * 64, &vtl[p ^ 1][(t + 256 * u) * 8]);
        #pragma unroll
        for (int jb = 0; jb < 4; ++jb)
            kpre[jb] = *(const v8s*)(kbase + (jn * 64 + 16 * jb) * CDH);
        apre0 = *(const int2*)(abase + jn * 64);
        apre1 = *(const int2*)(abase + jn * 64 + 32);

        // ---- softmax numerators, all in registers ----
        float pv[4][4];   // [jb][rr] = P[i=l15][j=16jb+4quad+rr]
        #pragma unroll
        for (int jb = 0; jb < 4; ++jb)
            #pragma unroll
            for (int rr = 0; rr < 4; ++rr) pv[jb][rr] = exp2f(sacc[jb][rr]);
        plsum += ((pv[0][0] + pv[0][1]) + (pv[0][2] + pv[0][3]))
               + ((pv[1][0] + pv[1][1]) + (pv[1][2] + pv[1][3]))
               + ((pv[2][0] + pv[2][1]) + (pv[2][2] + pv[2][3]))
               + ((pv[3][0] + pv[3][1]) + (pv[3][2] + pv[3][3]));

        // ---- PV: pack P pairs, byte-LUT masks, MFMA from registers ----
        #pragma unroll
        for (int kb = 0; kb < 2; ++kb) {
            // A-operand dwords: e = {0..7} = rr of jb=kb then rr of jb=kb+2
            const unsigned P[4] = {
                cvtpk_bf16(pv[kb][0],     pv[kb][1]),
                cvtpk_bf16(pv[kb][2],     pv[kb][3]),
                cvtpk_bf16(pv[kb + 2][0], pv[kb + 2][1]),
                cvtpk_bf16(pv[kb + 2][2], pv[kb + 2][3])};
            const int2 aa = kb ? a1 : a0;
            // D[u] = [v0,v0,v1,v1] bytes for pair u
            const unsigned D[4] = {
                __builtin_amdgcn_perm((unsigned)aa.x, (unsigned)aa.x, 0x01010000u),
                __builtin_amdgcn_perm((unsigned)aa.x, (unsigned)aa.x, 0x03030202u),
                __builtin_amdgcn_perm((unsigned)aa.y, (unsigned)aa.y, 0x01010000u),
                __builtin_amdgcn_perm((unsigned)aa.y, (unsigned)aa.y, 0x03030202u)};
            #pragma unroll
            for (int r = 0; r < 4; ++r) {
                const unsigned tb = 0xffu << (8 * r);   // one-hot byte table
                unsigned pf[4];
                #pragma unroll
                for (int u = 0; u < 4; ++u)
                    pf[u] = P[u] & __builtin_amdgcn_perm(0u, tb, D[u]);
                const v8s pfr = __builtin_bit_cast(v8s,
                    make_uint4(pf[0], pf[1], pf[2], pf[3]));
                #pragma unroll
                for (int cb = 0; cb < 2; ++cb) {
                    const v8s vfrag = *(const v8s*)&vtl[p][r * 2048 +
                        (16 * cb + l15) * 64 + (((4 * kb + quad) * 8) ^ psw)];
                    oacc[cb] = __builtin_amdgcn_mfma_f32_16x16x32_bf16(
                        pfr, vfrag, oacc[cb], 0, 0, 0);
                }
            }
        }
    }

    // ---- epilogue: reduce plsum over quads, redistribute, normalize ----
    float plF = plsum;
    plF += __shfl_xor(plF, 16);
    plF += __shfl_xor(plF, 32);            // lane x: denom for row i=x&15
    #pragma unroll
    for (int rr = 0; rr < 4; ++rr) {
        const float inv = 1.f / __shfl(plF, quad * 4 + rr);
        const int row = i0 + 16 * w + quad * 4 + rr;
        #pragma unroll
        for (int cb = 0; cb < 2; ++cb)
            outh[((size_t)b * CN + row) * CD + h * CDH + 16 * cb + l15] =
                f2bf(oacc[cb][rr] * inv);
    }
}

// ---------------------------------------------------------------------------
extern "C" void kernel_launch(void* const* d_in, const int* in_sizes, int n_in,
                              void* d_out, int out_size, void* d_ws, size_t ws_size,
                              hipStream_t stream)
{
    const float* src = (const float*)d_in[0];
    const int*   adj = (const int*)d_in[1];
    const float* Wq  = (const float*)d_in[2];
    const float* bq  = (const float*)d_in[3];
    const float* Wk  = (const float*)d_in[4];
    const float* bk  = (const float*)d_in[5];
    const float* Wv  = (const float*)d_in[6];
    const float* bv  = (const float*)d_in[7];
    const float* Wo  = (const float*)d_in[8];
    const float* bo  = (const float*)d_in[9];
    const float* W1  = (const float*)d_in[10];
    const float* b1  = (const float*)d_in[11];
    const float* W2  = (const float*)d_in[12];
    const float* b2  = (const float*)d_in[13];
    const float* g1  = (const float*)d_in[14];
    const float* be1 = (const float*)d_in[15];
    const float* g2  = (const float*)d_in[16];
    const float* be2 = (const float*)d_in[17];
    float* out = (float*)d_out;

    char* wsb = (char*)d_ws;
    const size_t MB = (size_t)1 << 20;

    // workspace layout (42 MB with aliasing)
    unsigned char* adjsel = (unsigned char*)(wsb);          // [0,8) MB byte-pair adj
    short* qkv_bf = (short*)(wsb + 8 * MB);                 // [8,32): q,k planes + vT
    short* src_bf = (short*)(wsb + 32 * MB);                // [32,36)
    short* wqkvT  = (short*)(wsb + 36 * MB);                // 768 KB
    short* woT    = (short*)(wsb + 36 * MB + 768 * 1024);   // 128 KB
    short* w1T    = (short*)(wsb + 36 * MB + 896 * 1024);   // 512 KB
    short* w2T    = (short*)(wsb + 36 * MB + 1408 * 1024);  // 512 KB
    float* bpack  = (float*)(wsb + 36 * MB + 1920 * 1024);  // 12 KB
    short* heads_bf = (short*)(wsb + 38 * MB);              // [38,42)
    short* x_bf   = (short*)(wsb + 32 * MB);                // reuse src_bf (LN1 out)
    short* h1_bf  = (short*)(wsb + 16 * MB);                // reuse vT (dead post-attn)

    const int M = CB * CN;        // 8192
    dim3 blk(256);

    // prep: src cast, coalesced weight transposes, biases (2300 blocks)
    prep<<<dim3(2300), blk, 0, stream>>>(src, Wq, Wk, Wv, Wo, W1, W2,
        bq, bk, bv, bo, b1, b2, src_bf, wqkvT, woT, w1T, w2T, bpack);

    // fused QK + V^T projection (128x128 tiles) + sigma byte pack: 1280 blocks
    proj_kernel<<<dim3(1280), blk, 32768, stream>>>(
        src_bf, wqkvT, bpack, qkv_bf, adj, adjsel);

    // fused relational MFMA attention (XCD-aware 1D grid) -> bf16 heads
    attn_mfma<<<dim3(1024), blk, 0, stream>>>(
        qkv_bf, qkv_bf + SZH, qkv_bf + 2 * SZH, adjsel, heads_bf);

    // O-projection + bias + residual(src fp32) + LN1 -> x_bf bf16 only
    gemm_ln32<false, true, false><<<dim3(M / 16), blk, 0, stream>>>(
        heads_bf, woT, bpack + 1536, src, g1, be1, nullptr, x_bf, CD);

    // FFN1 (128x128 tiles): 512 blocks
    gemm_mfma<128, 128, MODE_FFN1><<<dim3(M / 128, CFF / 128), blk, 32768, stream>>>(
        x_bf, w1T, bpack + 1792, h1_bf, M, CD, CFF);

    // FFN2 + bias + residual(x_bf bf16) + LN2 -> out fp32
    gemm_ln32<true, false, true><<<dim3(M / 16), blk, 0, stream>>>(
        h1_bf, w2T, bpack + 2816, x_bf, g2, be2, out, nullptr, CFF);
}

// Round 6
// 216.836 us; speedup vs baseline: 1.0749x; 1.0404x over previous
//
#include <hip/hip_runtime.h>
#include <hip/hip_bf16.h>
#include <cmath>

// Problem constants (fixed by the reference)
constexpr int CB  = 8;     // batch
constexpr int CN  = 1024;  // sequence length
constexpr int CD  = 256;   // model dim
constexpr int CH  = 8;     // heads
constexpr int CDH = 32;    // head dim
constexpr int CR  = 4;     // relation types (adj value 4 = none)
constexpr int CFF = 1024;  // ffn dim
constexpr float CEPS = 1e-5f;
constexpr float CS = 0.25503480f;   // (1/sqrt(32)) * log2(e), folded into Q
constexpr size_t SZH = (size_t)CB * CH * CN * CDH;  // 2M: one head-plane

#define MODE_QK    0   // scatter bf16 q/k head-major planes, +bias (cols 0..511)
#define MODE_FFN1  2   // +bias, tanh-gelu -> bf16
#define MODE_VT    4   // V^T gemm (A=weight rows, B=src rows): sigma column store

typedef float v4f __attribute__((ext_vector_type(4)));
typedef short v8s __attribute__((ext_vector_type(8)));

static __device__ __forceinline__ short f2bf(float f) {
    unsigned u = __builtin_bit_cast(unsigned, f);
    u += 0x7fff + ((u >> 16) & 1);          // round-to-nearest-even
    return (short)(u >> 16);
}
static __device__ __forceinline__ float bf2f(short s) {
    unsigned u = ((unsigned)(unsigned short)s) << 16;
    return __builtin_bit_cast(float, u);
}
static __device__ __forceinline__ unsigned cvtpk_bf16(float lo, float hi) {
    unsigned r;
    asm("v_cvt_pk_bf16_f32 %0, %1, %2" : "=v"(r) : "v"(lo), "v"(hi));
    return r;
}

static __device__ __forceinline__ void async_copy16(const void* g, void* l) {
    __builtin_amdgcn_global_load_lds(
        (const __attribute__((address_space(1))) void*)g,
        (__attribute__((address_space(3))) void*)l, 16, 0, 0);
}

// PV k-order permutation sigma(j): c[5]=j[4], c[4:3]=j[3:2], c[2]=j[5],
// c[1:0]=j[1:0].  With swapped QK^T (sacc = mfma(K,Q)), lane (quad,l15)
// holds P[i=l15][j=16jb+4quad+rr], and sigma maps those 16 j's exactly onto
// PV A-operand k-slots {kb*32 + quad*8 + e} -> P never touches LDS.
// adjsel stores adj as BYTES in sigma pair order; at PV time the byte value
// itself is a v_perm selector into a one-hot 0xff table (v=4 -> zero operand).

// ---------------------------------------------------------------------------
// bf16 MFMA GEMM body (device fn, dynamic LDS): epilogue(A[M,K] @ Bw[N,K])
// BM x BN tile, 4 waves 2x2, BK=32 double-buffered 1-deep prefetch.
// ---------------------------------------------------------------------------
template<int BM, int BN, int MODE>
__device__ __forceinline__ void gemm_body(
    const short* __restrict__ A, const short* __restrict__ Bw,
    const float* __restrict__ biasv, void* __restrict__ dest,
    int M, int K, int Nw, int bx, int by, short* smem)
{
    constexpr int WTM = BM / 2, WTN = BN / 2;
    constexpr int TM = WTM / 16, TN = WTN / 16;
    short* As = smem;                    // [2][BM*32]
    short* Bs = smem + 2 * BM * 32;      // [2][BN*32]

    const int t    = threadIdx.x;
    const int lane = t & 63;
    const int w    = t >> 6;
    const int quad = lane >> 4, l15 = lane & 15;
    const int wm = w >> 1, wn = w & 1;
    const int m0 = bx * BM, n0 = by * BN;

    const int srow = lane >> 2;
    const int scol = (lane & 3) * 8;

    v4f acc[TM][TN];
    #pragma unroll
    for (int i = 0; i < TM; ++i)
        #pragma unroll
        for (int j = 0; j < TN; ++j) acc[i][j] = (v4f){0.f, 0.f, 0.f, 0.f};

    const int NK = K >> 5;

    auto stage = [&](int buf, int kt) {
        #pragma unroll
        for (int u = 0; u < BM / 64; ++u) {
            const int e0 = (w * (BM / 64) + u) * 512;
            const int row = (e0 >> 5) + srow;
            async_copy16(A + (size_t)(m0 + row) * K + kt + scol,
                         &As[buf * BM * 32 + e0]);
        }
        #pragma unroll
        for (int u = 0; u < BN / 64; ++u) {
            const int e0 = (w * (BN / 64) + u) * 512;
            const int row = (e0 >> 5) + srow;
            async_copy16(Bw + (size_t)(n0 + row) * K + kt + scol,
                         &Bs[buf * BN * 32 + e0]);
        }
    };

    stage(0, 0);

    for (int it = 0; it < NK; ++it) {
        __syncthreads();
        if (it + 1 < NK) stage((it + 1) & 1, (it + 1) << 5);

        const int buf = it & 1;
        v8s af[TM], bfr[TN];
        #pragma unroll
        for (int i = 0; i < TM; ++i)
            af[i] = *(const v8s*)&As[buf * BM * 32 +
                                     (wm * WTM + i * 16 + l15) * 32 + quad * 8];
        #pragma unroll
        for (int j = 0; j < TN; ++j)
            bfr[j] = *(const v8s*)&Bs[buf * BN * 32 +
                                      (wn * WTN + j * 16 + l15) * 32 + quad * 8];
        #pragma unroll
        for (int i = 0; i < TM; ++i)
            #pragma unroll
            for (int j = 0; j < TN; ++j)
                acc[i][j] = __builtin_amdgcn_mfma_f32_16x16x32_bf16(
                    af[i], bfr[j], acc[i][j], 0, 0, 0);
    }

    #pragma unroll
    for (int i = 0; i < TM; ++i) {
        #pragma unroll
        for (int j = 0; j < TN; ++j) {
            const int mb = m0 + wm * WTM + i * 16 + quad * 4;   // row of rr=0
            const int n  = n0 + wn * WTN + j * 16 + l15;
            float vals[4];
            if (MODE == MODE_VT) {
                #pragma unroll
                for (int rr = 0; rr < 4; ++rr) vals[rr] = acc[i][j][rr] + biasv[mb + rr];
            } else {
                #pragma unroll
                for (int rr = 0; rr < 4; ++rr) vals[rr] = acc[i][j][rr] + biasv[n];
            }

            if (MODE == MODE_QK) {
                // fold softmax scale into Q (q-plane blocks have n0 < 256)
                if (n0 < 256) {
                    #pragma unroll
                    for (int rr = 0; rr < 4; ++rr) vals[rr] *= CS;
                }
                const int b = mb >> 10, ii0 = mb & 1023;
                const int plane = n >> 8, nn = n & 255;
                const int h = nn >> 5, d = nn & 31;
                #pragma unroll
                for (int rr = 0; rr < 4; ++rr)
                    ((short*)dest)[(size_t)plane * SZH +
                        (((size_t)(b * CH + h)) * CN + ii0 + rr) * CDH + d] =
                        f2bf(vals[rr]);
            } else if (MODE == MODE_VT) {
                // sigma column permutation within each 64-token tile (see top)
                const int b = n >> 10, ii = n & 1023;
                const int jj = ii & 63;
                const int cc = (((jj >> 4) & 1) << 5) | (((jj >> 2) & 3) << 3) |
                               (((jj >> 5) & 1) << 2) | (jj & 3);
                const int iip = (ii & ~63) | cc;
                #pragma unroll
                for (int rr = 0; rr < 4; ++rr) {
                    const int m = mb + rr;
                    const int r2 = m >> 8, hd = m & 255;
                    const int h = hd >> 5, d = hd & 31;
                    ((short*)dest)[2 * SZH +
                        (((size_t)(r2 * 64 + b * CH + h)) * CDH + d) * CN + iip] =
                        f2bf(vals[rr]);
                }
            } else { // MODE_FFN1: tanh-gelu -> bf16 (x*E/(E+1))
                #pragma unroll
                for (int rr = 0; rr < 4; ++rr) {
                    const size_t idx = (size_t)(mb + rr) * Nw + n;
                    const float xx = vals[rr];
                    const float E = exp2f(2.302217f * (xx + 0.044715f * xx * xx * xx));
                    ((short*)dest)[idx] = f2bf(xx * E / (E + 1.f));
                }
            }
        }
    }
}

template<int BM, int BN, int MODE>
__global__ __launch_bounds__(256)
void gemm_mfma(const short* __restrict__ A, const short* __restrict__ Bw,
               const float* __restrict__ biasv, void* __restrict__ dest,
               int M, int K, int Nw)
{
    extern __shared__ short smem[];
    gemm_body<BM, BN, MODE>(A, Bw, biasv, dest, M, K, Nw,
                            blockIdx.x, blockIdx.y, smem);
}

// ---------------------------------------------------------------------------
// Fused projection dispatch (128x128 m97-style tiles):
//   blocks 0..255   = QK  (8192x512, K=256)
//   blocks 256..767 = V^T (1024x8192, K=256)
//   blocks 768..1279= adj int32 -> BYTE-pair pack in sigma order (adjsel)
// ---------------------------------------------------------------------------
__global__ __launch_bounds__(256)
void proj_kernel(const short* __restrict__ src_bf, const short* __restrict__ wqkvT,
                 const float* __restrict__ bpack, short* __restrict__ qkv,
                 const int* __restrict__ adj, unsigned char* __restrict__ adjsel)
{
    extern __shared__ short smem[];
    const int g = blockIdx.x;
    if (g < 256) {
        gemm_body<128, 128, MODE_QK>(src_bf, wqkvT, bpack, qkv,
                                     8192, 256, 512, g >> 2, g & 3, smem);
    } else if (g < 768) {
        const int h2 = g - 256;
        gemm_body<128, 128, MODE_VT>(wqkvT + 512 * 256, src_bf, bpack + 512,
                                     qkv, 1024, 256, 8192, h2 & 7, h2 >> 3, smem);
    } else {
        // sigma-order byte pack: int2 (row, dwi) holds adj bytes for the 8 j's
        // j0+{0..3}, j0+32+{0..3} with j0 = T*64 + (kq&3)*4 + (kq>>2)*16,
        // T = dwi>>3, kq = dwi&7  (kq = kb*4 + quad).
        const int nout = CB * CN * CN / 8;           // 1M int2 (8 j's each)
        for (int i = (g - 768) * 256 + threadIdx.x; i < nout; i += 512 * 256) {
            const int dwi = i & 127;
            const int row = i >> 7;
            const int T   = dwi >> 3, kq = dwi & 7;
            const int j0  = T * 64 + (kq & 3) * 4 + (kq >> 2) * 16;
            const int* p = adj + (size_t)row * CN + j0;
            const int4 q0 = *(const int4*)(p);
            const int4 q1 = *(const int4*)(p + 32);
            int2 o;
            o.x = (q0.x & 0xff) | ((q0.y & 0xff) << 8) |
                  ((q0.z & 0xff) << 16) | ((q0.w & 0xff) << 24);
            o.y = (q1.x & 0xff) | ((q1.y & 0xff) << 8) |
                  ((q1.z & 0xff) << 16) | ((q1.w & 0xff) << 24);
            ((int2*)adjsel)[i] = o;
        }
    }
}

// ---------------------------------------------------------------------------
// FUSED GEMM + bias + residual + LayerNorm, BM=16, BK=64 (half the barriers
// of BK=32; 8 MFMA per wave between barriers).  Granule-XOR swizzle on the
// 128B-stride LDS rows (source-side, linear dest) -> conflict-light reads.
// OUTF: write fp32 result; OUTB: write bf16 result; ADDBF: residual is bf16.
// ---------------------------------------------------------------------------
template<bool OUTF, bool OUTB, bool ADDBF>
__global__ __launch_bounds__(256)
void gemm_ln32(const short* __restrict__ A, const short* __restrict__ Bw,
               const float* __restrict__ biasv, const void* __restrict__ addp,
               const float* __restrict__ gw, const float* __restrict__ be,
               float* __restrict__ outf, short* __restrict__ outb, int K)
{
    __shared__ short As[2][16 * 64];
    __shared__ short Bs[2][256 * 64];
    __shared__ float redS[16][4], redQ[16][4];

    const int t    = threadIdx.x;
    const int lane = t & 63;
    const int w    = t >> 6;          // wave -> column quarter (64 cols)
    const int quad = lane >> 4, l15 = lane & 15;
    const int m0   = blockIdx.x * 16;
    const int xsw  = l15 & 7;         // read-side granule XOR

    v4f acc[4];
    #pragma unroll
    for (int j = 0; j < 4; ++j) acc[j] = (v4f){0.f, 0.f, 0.f, 0.f};

    const int NK = K >> 6;

    auto stage = [&](int buf, int kt) {
        if (t < 128) {   // A: 16 rows x 64 cols = 128 granules
            const int row = t >> 3, gc = t & 7;
            async_copy16(A + (size_t)(m0 + row) * K + kt + ((gc ^ (row & 7)) * 8),
                         &As[buf][t * 8]);
        }
        #pragma unroll
        for (int u = 0; u < 8; ++u) {   // B: 256 rows x 64 cols = 2048 granules
            const int gl = t + 256 * u;
            const int row = gl >> 3, gc = gl & 7;
            async_copy16(Bw + (size_t)row * K + kt + ((gc ^ (row & 7)) * 8),
                         &Bs[buf][gl * 8]);
        }
    };

    stage(0, 0);

    for (int it = 0; it < NK; ++it) {
        __syncthreads();
        if (it + 1 < NK) stage((it + 1) & 1, (it + 1) << 6);

        const int buf = it & 1;
        #pragma unroll
        for (int half = 0; half < 2; ++half) {
            const int gr = (quad + 4 * half) ^ xsw;
            const v8s af = *(const v8s*)&As[buf][l15 * 64 + gr * 8];
            #pragma unroll
            for (int j = 0; j < 4; ++j) {
                const v8s bfr = *(const v8s*)&Bs[buf][(w * 64 + 16 * j + l15) * 64 + gr * 8];
                acc[j] = __builtin_amdgcn_mfma_f32_16x16x32_bf16(af, bfr, acc[j], 0, 0, 0);
            }
        }
    }

    float v[4][4];
    #pragma unroll
    for (int rr = 0; rr < 4; ++rr) {
        const int row = m0 + quad * 4 + rr;
        float s = 0.f, sq = 0.f;
        #pragma unroll
        for (int j = 0; j < 4; ++j) {
            const int n = w * 64 + 16 * j + l15;
            const size_t idx = (size_t)row * CD + n;
            const float addv = ADDBF ? bf2f(((const short*)addp)[idx])
                                     : ((const float*)addp)[idx];
            const float x = acc[j][rr] + biasv[n] + addv;
            v[rr][j] = x;
            s += x; sq += x * x;
        }
        #pragma unroll
        for (int off = 1; off < 16; off <<= 1) {
            s  += __shfl_xor(s, off);
            sq += __shfl_xor(sq, off);
        }
        if (l15 == 0) {
            redS[quad * 4 + rr][w] = s;
            redQ[quad * 4 + rr][w] = sq;
        }
    }
    __syncthreads();

    #pragma unroll
    for (int rr = 0; rr < 4; ++rr) {
        const int r16 = quad * 4 + rr;
        const int row = m0 + r16;
        const float s  = (redS[r16][0] + redS[r16][1]) + (redS[r16][2] + redS[r16][3]);
        const float sq = (redQ[r16][0] + redQ[r16][1]) + (redQ[r16][2] + redQ[r16][3]);
        const float mean = s * (1.f / CD);
        const float var  = sq * (1.f / CD) - mean * mean;
        const float rstd = rsqrtf(var + CEPS);
        #pragma unroll
        for (int j = 0; j < 4; ++j) {
            const int n = w * 64 + 16 * j + l15;
            const float y = (v[rr][j] - mean) * rstd * gw[n] + be[n];
            if (OUTF) outf[(size_t)row * CD + n] = y;
            if (OUTB) outb[(size_t)row * CD + n] = f2bf(y);
        }
    }
}

// ---------------------------------------------------------------------------
// Prep: src->bf16, weight transposes via 64x64 LDS tiles, biases packed.
// ---------------------------------------------------------------------------
__global__ __launch_bounds__(256)
void prep(const float* __restrict__ src,
          const float* __restrict__ Wq, const float* __restrict__ Wk,
          const float* __restrict__ Wv, const float* __restrict__ Wo,
          const float* __restrict__ W1, const float* __restrict__ W2,
          const float* __restrict__ bq, const float* __restrict__ bk,
          const float* __restrict__ bv, const float* __restrict__ bo,
          const float* __restrict__ b1, const float* __restrict__ b2,
          short* __restrict__ src_bf,
          short* __restrict__ wqkvT, short* __restrict__ woT,
          short* __restrict__ w1T, short* __restrict__ w2T,
          float* __restrict__ bpack)
{
    __shared__ float tile[64][65];
    const int bx = blockIdx.x, t = threadIdx.x;
    if (bx < 2048) {                                   // src cast: 512K float4
        const int i = bx * 256 + t;
        const float4 v = ((const float4*)src)[i];
        short4 o;
        o.x = f2bf(v.x); o.y = f2bf(v.y); o.z = f2bf(v.z); o.w = f2bf(v.w);
        ((short4*)src_bf)[i] = o;
    } else if (bx < 2288) {                            // weight transposes
        const int tt = bx - 2048;
        const float* S; short* D;
        int Sstride, Dstride, k0, srccol, dstrow;
        if (tt < 96) {                                 // wqkv: 24x4 tiles
            const int tk = tt & 3, tn = tt >> 2;
            const int ng = tn * 64;
            Sstride = 256; Dstride = 256; k0 = tk * 64;
            dstrow = tn * 64; D = wqkvT;
            if (ng < 256)      { S = Wq; srccol = ng; }
            else if (ng < 512) { S = Wk; srccol = ng - 256; }
            else { const int r = (ng - 512) >> 8;
                   S = Wv + (size_t)r * 65536; srccol = (ng - 512) & 255; }
        } else if (tt < 112) {                         // wo: 4x4
            const int u = tt - 96, tk = u & 3, tn = u >> 2;
            S = Wo; Sstride = 256; D = woT; Dstride = 256;
            k0 = tk * 64; srccol = tn * 64; dstrow = tn * 64;
        } else if (tt < 176) {                         // w1: 16x4
            const int u = tt - 112, tk = u & 3, tn = u >> 2;
            S = W1; Sstride = 1024; D = w1T; Dstride = 256;
            k0 = tk * 64; srccol = tn * 64; dstrow = tn * 64;
        } else {                                       // w2: 4x16
            const int u = tt - 176, tk = u & 15, tn = u >> 4;
            S = W2; Sstride = 256; D = w2T; Dstride = 1024;
            k0 = tk * 64; srccol = tn * 64; dstrow = tn * 64;
        }
        #pragma unroll
        for (int u2 = 0; u2 < 4; ++u2) {               // coalesced read
            const int kl = (t >> 4) + u2 * 16;
            const int nl = (t & 15) * 4;
            const float4 v = *(const float4*)&S[(size_t)(k0 + kl) * Sstride + srccol + nl];
            tile[kl][nl + 0] = v.x; tile[kl][nl + 1] = v.y;
            tile[kl][nl + 2] = v.z; tile[kl][nl + 3] = v.w;
        }
        __syncthreads();
        #pragma unroll
        for (int u2 = 0; u2 < 4; ++u2) {               // coalesced write
            const int nl = (t >> 4) + u2 * 16;
            const int kl = (t & 15) * 4;
            short4 o;
            o.x = f2bf(tile[kl + 0][nl]); o.y = f2bf(tile[kl + 1][nl]);
            o.z = f2bf(tile[kl + 2][nl]); o.w = f2bf(tile[kl + 3][nl]);
            *(short4*)&D[(size_t)(dstrow + nl) * Dstride + k0 + kl] = o;
        }
    } else {                                           // biases: 3072
        const int idx = (bx - 2288) * 256 + t;
        float bvv;
        if (idx < 256)       bvv = bq[idx];
        else if (idx < 512)  bvv = bk[idx - 256];
        else if (idx < 1536) bvv = bv[idx - 512];
        else if (idx < 1792) bvv = bo[idx - 1536];
        else if (idx < 2816) bvv = b1[idx - 1792];
        else                 bvv = b2[idx - 2816];
        bpack[idx] = bvv;
    }
}

// ---------------------------------------------------------------------------
// Fused relational attention, register-resident P + byte-LUT masks + ILP:
//  - QK^T swapped (sacc = mfma(K,Q)) -> P lane-local; sigma k-order feeds PV
//  - per-kb vfrag batch-load (8 ds_read_b128 issued before the mask VALU
//    block, which hides their latency) -> no serial read->MFMA chain
//  - split accumulators oacc[cb][kb] (MFMA dep chain 4 deep, not 8)
//  - s_setprio(1) around the pure-MFMA clusters (T5)
//  - V^T staged by global_load_lds 2-deep ring; K/adjsel direct from L2
// One __syncthreads per j-tile.  XCD-aware 1D grid (b = g & 7).
// ---------------------------------------------------------------------------
__global__ __launch_bounds__(256, 4)
void attn_mfma(const short* __restrict__ qg, const short* __restrict__ kg,
               const short* __restrict__ vt, const unsigned char* __restrict__ adjsel,
               short* __restrict__ outh)
{
    __shared__ __align__(16) short vtl[2][8192];  // [buf][r*2048 + d*64 + gc*8]

    const int t    = threadIdx.x;
    const int lane = t & 63;
    const int w    = t >> 6;          // wave 0..3
    const int quad = lane >> 4;
    const int l15  = lane & 15;
    const int g    = blockIdx.x;      // 1D grid, XCD-aware decode
    const int b    = g & 7;           // same XCD for whole batch
    const int h    = (g >> 3) & 7;
    const int i0   = (g >> 6) * 64;
    const int bhh  = b * CH + h;
    const size_t bh = (size_t)bhh;

    const v8s qfrag = *(const v8s*)&qg[(bh * CN + i0 + 16 * w + l15) * CDH + quad * 8];

    // V DMA sources: thread t stages granule gl = t + 256u; LDS granule
    // (r,d,gc) holds global granule gc^(d&7) of V^T row (r,d) in this j-tile.
    const short* vsrc[4];
    #pragma unroll
    for (int u = 0; u < 4; ++u) {
        const int gl = t + 256 * u;
        const int r = gl >> 8, d = (gl >> 3) & 31, gc = gl & 7;
        vsrc[u] = vt + ((size_t)(r * 64 + bhh) * CDH + d) * CN + (gc ^ (d & 7)) * 8;
    }
    // K direct: A-operand rows l15, k-chunk quad*8
    const short* kbase = kg + (bh * CN + l15) * CDH + quad * 8;
    // adjsel direct: row i0+16w+l15, int2 (kb, quad) of the 64B tile slice
    const unsigned char* abase =
        adjsel + ((size_t)(b * CN) + i0 + 16 * w + l15) * CN + quad * 8;

    v4f oacc[2][2];                    // [cb][kb] split accumulators
    #pragma unroll
    for (int cb = 0; cb < 2; ++cb)
        #pragma unroll
        for (int kb = 0; kb < 2; ++kb) oacc[cb][kb] = (v4f){0.f, 0.f, 0.f, 0.f};
    float plsum = 0.f;                     // lane-local: row i=l15, this quad's j's
    const int psw = (l15 & 7) * 8;         // vfrag granule XOR (pre-scaled)

    // ---- prologue: prefetch tile 0 ----
    #pragma unroll
    for (int u = 0; u < 4; ++u)
        async_copy16(vsrc[u], &vtl[0][(t + 256 * u) * 8]);
    v8s kpre[4];
    #pragma unroll
    for (int jb = 0; jb < 4; ++jb)
        kpre[jb] = *(const v8s*)(kbase + (16 * jb) * CDH);
    int2 apre0 = *(const int2*)(abase);
    int2 apre1 = *(const int2*)(abase + 32);

    for (int jt = 0; jt < 16; ++jt) {
        __syncthreads();   // vtl[jt&1] staged; other buf free for prefetch
        const int p = jt & 1;

        // ---- QK swapped: sacc[jb] row=j-local, col=i-local ----
        v4f sacc[4];
        #pragma unroll
        for (int jb = 0; jb < 4; ++jb)
            sacc[jb] = __builtin_amdgcn_mfma_f32_16x16x32_bf16(
                kpre[jb], qfrag, (v4f){0.f, 0.f, 0.f, 0.f}, 0, 0, 0);

        // ---- issue prefetches for tile jt+1 (wrap harmless on last iter) ----
        const int2 a0 = apre0, a1 = apre1;
        const int jn = (jt + 1) & 15;
        #pragma unroll
        for (int u = 0; u < 4; ++u)
            async_copy16(vsrc[u] + jn * 64, &vtl[p ^ 1][(t + 256 * u) * 8]);
        #pragma unroll
        for (int jb = 0; jb < 4; ++jb)
            kpre[jb] = *(const v8s*)(kbase + (jn * 64 + 16 * jb) * CDH);
        apre0 = *(const int2*)(abase + jn * 64);
        apre1 = *(const int2*)(abase + jn * 64 + 32);

        // ---- softmax numerators, all in registers ----
        float pv[4][4];   // [jb][rr] = P[i=l15][j=16jb+4quad+rr]
        #pragma unroll
        for (int jb = 0; jb < 4; ++jb)
            #pragma unroll
            for (int rr = 0; rr < 4; ++rr) pv[jb][rr] = exp2f(sacc[jb][rr]);
        plsum += ((pv[0][0] + pv[0][1]) + (pv[0][2] + pv[0][3]))
               + ((pv[1][0] + pv[1][1]) + (pv[1][2] + pv[1][3]))
               + ((pv[2][0] + pv[2][1]) + (pv[2][2] + pv[2][3]))
               + ((pv[3][0] + pv[3][1]) + (pv[3][2] + pv[3][3]));

        // ---- PV: per-kb vfrag batch load, byte-LUT masks, MFMA cluster ----
        #pragma unroll
        for (int kb = 0; kb < 2; ++kb) {
            // batch-issue the 8 ds_read_b128 for this kb (latency hidden
            // under the mask VALU block below)
            v8s vf[4][2];
            #pragma unroll
            for (int r = 0; r < 4; ++r)
                #pragma unroll
                for (int cb = 0; cb < 2; ++cb)
                    vf[r][cb] = *(const v8s*)&vtl[p][r * 2048 +
                        (16 * cb + l15) * 64 + (((4 * kb + quad) * 8) ^ psw)];

            // A-operand dwords: e = {0..7} = rr of jb=kb then rr of jb=kb+2
            const unsigned P[4] = {
                cvtpk_bf16(pv[kb][0],     pv[kb][1]),
                cvtpk_bf16(pv[kb][2],     pv[kb][3]),
                cvtpk_bf16(pv[kb + 2][0], pv[kb + 2][1]),
                cvtpk_bf16(pv[kb + 2][2], pv[kb + 2][3])};
            const int2 aa = kb ? a1 : a0;
            // D[u] = [v0,v0,v1,v1] bytes for pair u
            const unsigned D[4] = {
                __builtin_amdgcn_perm((unsigned)aa.x, (unsigned)aa.x, 0x01010000u),
                __builtin_amdgcn_perm((unsigned)aa.x, (unsigned)aa.x, 0x03030202u),
                __builtin_amdgcn_perm((unsigned)aa.y, (unsigned)aa.y, 0x01010000u),
                __builtin_amdgcn_perm((unsigned)aa.y, (unsigned)aa.y, 0x03030202u)};
            unsigned pfm[4][4];
            #pragma unroll
            for (int r = 0; r < 4; ++r) {
                const unsigned tb = 0xffu << (8 * r);   // one-hot byte table
                #pragma unroll
                for (int u = 0; u < 4; ++u)
                    pfm[r][u] = P[u] & __builtin_amdgcn_perm(0u, tb, D[u]);
            }
            __builtin_amdgcn_s_setprio(1);
            #pragma unroll
            for (int r = 0; r < 4; ++r) {
                const v8s pfr = __builtin_bit_cast(v8s,
                    make_uint4(pfm[r][0], pfm[r][1], pfm[r][2], pfm[r][3]));
                #pragma unroll
                for (int cb = 0; cb < 2; ++cb)
                    oacc[cb][kb] = __builtin_amdgcn_mfma_f32_16x16x32_bf16(
                        pfr, vf[r][cb], oacc[cb][kb], 0, 0, 0);
            }
            __builtin_amdgcn_s_setprio(0);
        }
    }

    // ---- epilogue: merge split accumulators, reduce plsum, normalize ----
    v4f ofin[2];
    ofin[0] = oacc[0][0] + oacc[0][1];
    ofin[1] = oacc[1][0] + oacc[1][1];
    float plF = plsum;
    plF += __shfl_xor(plF, 16);
    plF += __shfl_xor(plF, 32);            // lane x: denom for row i=x&15
    #pragma unroll
    for (int rr = 0; rr < 4; ++rr) {
        const float inv = 1.f / __shfl(plF, quad * 4 + rr);
        const int row = i0 + 16 * w + quad * 4 + rr;
        #pragma unroll
        for (int cb = 0; cb < 2; ++cb)
            outh[((size_t)b * CN + row) * CD + h * CDH + 16 * cb + l15] =
                f2bf(ofin[cb][rr] * inv);
    }
}

// ---------------------------------------------------------------------------
extern "C" void kernel_launch(void* const* d_in, const int* in_sizes, int n_in,
                              void* d_out, int out_size, void* d_ws, size_t ws_size,
                              hipStream_t stream)
{
    const float* src = (const float*)d_in[0];
    const int*   adj = (const int*)d_in[1];
    const float* Wq  = (const float*)d_in[2];
    const float* bq  = (const float*)d_in[3];
    const float* Wk  = (const float*)d_in[4];
    const float* bk  = (const float*)d_in[5];
    const float* Wv  = (const float*)d_in[6];
    const float* bv  = (const float*)d_in[7];
    const float* Wo  = (const float*)d_in[8];
    const float* bo  = (const float*)d_in[9];
    const float* W1  = (const float*)d_in[10];
    const float* b1  = (const float*)d_in[11];
    const float* W2  = (const float*)d_in[12];
    const float* b2  = (const float*)d_in[13];
    const float* g1  = (const float*)d_in[14];
    const float* be1 = (const float*)d_in[15];
    const float* g2  = (const float*)d_in[16];
    const float* be2 = (const float*)d_in[17];
    float* out = (float*)d_out;

    char* wsb = (char*)d_ws;
    const size_t MB = (size_t)1 << 20;

    // workspace layout (42 MB with aliasing)
    unsigned char* adjsel = (unsigned char*)(wsb);          // [0,8) MB byte-pair adj
    short* qkv_bf = (short*)(wsb + 8 * MB);                 // [8,32): q,k planes + vT
    short* src_bf = (short*)(wsb + 32 * MB);                // [32,36)
    short* wqkvT  = (short*)(wsb + 36 * MB);                // 768 KB
    short* woT    = (short*)(wsb + 36 * MB + 768 * 1024);   // 128 KB
    short* w1T    = (short*)(wsb + 36 * MB + 896 * 1024);   // 512 KB
    short* w2T    = (short*)(wsb + 36 * MB + 1408 * 1024);  // 512 KB
    float* bpack  = (float*)(wsb + 36 * MB + 1920 * 1024);  // 12 KB
    short* heads_bf = (short*)(wsb + 38 * MB);              // [38,42)
    short* x_bf   = (short*)(wsb + 32 * MB);                // reuse src_bf (LN1 out)
    short* h1_bf  = (short*)(wsb + 16 * MB);                // reuse vT (dead post-attn)

    const int M = CB * CN;        // 8192
    dim3 blk(256);

    // prep: src cast, coalesced weight transposes, biases (2300 blocks)
    prep<<<dim3(2300), blk, 0, stream>>>(src, Wq, Wk, Wv, Wo, W1, W2,
        bq, bk, bv, bo, b1, b2, src_bf, wqkvT, woT, w1T, w2T, bpack);

    // fused QK + V^T projection (128x128 tiles) + sigma byte pack: 1280 blocks
    proj_kernel<<<dim3(1280), blk, 32768, stream>>>(
        src_bf, wqkvT, bpack, qkv_bf, adj, adjsel);

    // fused relational MFMA attention (XCD-aware 1D grid) -> bf16 heads
    attn_mfma<<<dim3(1024), blk, 0, stream>>>(
        qkv_bf, qkv_bf + SZH, qkv_bf + 2 * SZH, adjsel, heads_bf);

    // O-projection + bias + residual(src fp32) + LN1 -> x_bf bf16 only
    gemm_ln32<false, true, false><<<dim3(M / 16), blk, 0, stream>>>(
        heads_bf, woT, bpack + 1536, src, g1, be1, nullptr, x_bf, CD);

    // FFN1 (128x128 tiles): 512 blocks
    gemm_mfma<128, 128, MODE_FFN1><<<dim3(M / 128, CFF / 128), blk, 32768, stream>>>(
        x_bf, w1T, bpack + 1792, h1_bf, M, CD, CFF);

    // FFN2 + bias + residual(x_bf bf16) + LN2 -> out fp32
    gemm_ln32<true, false, true><<<dim3(M / 16), blk, 0, stream>>>(
        h1_bf, w2T, bpack + 2816, x_bf, g2, be2, out, nullptr, CFF);
}

// Round 7
// 209.610 us; speedup vs baseline: 1.1119x; 1.0345x over previous
//
#include <hip/hip_runtime.h>
#include <hip/hip_bf16.h>
#include <cmath>

// Problem constants (fixed by the reference)
constexpr int CB  = 8;     // batch
constexpr int CN  = 1024;  // sequence length
constexpr int CD  = 256;   // model dim
constexpr int CH  = 8;     // heads
constexpr int CDH = 32;    // head dim
constexpr int CR  = 4;     // relation types (adj value 4 = none)
constexpr int CFF = 1024;  // ffn dim
constexpr float CEPS = 1e-5f;
constexpr float CS = 0.25503480f;   // (1/sqrt(32)) * log2(e), folded into Q
constexpr size_t SZH = (size_t)CB * CH * CN * CDH;  // 2M: one head-plane

#define MODE_QK    0   // scatter bf16 q/k head-major planes, +bias (cols 0..511)
#define MODE_FFN1  2   // +bias, tanh-gelu -> bf16
#define MODE_VT    4   // V^T gemm (A=weight rows, B=src rows): sigma column store

typedef float v4f __attribute__((ext_vector_type(4)));
typedef short v8s __attribute__((ext_vector_type(8)));

static __device__ __forceinline__ short f2bf(float f) {
    unsigned u = __builtin_bit_cast(unsigned, f);
    u += 0x7fff + ((u >> 16) & 1);          // round-to-nearest-even
    return (short)(u >> 16);
}
static __device__ __forceinline__ float bf2f(short s) {
    unsigned u = ((unsigned)(unsigned short)s) << 16;
    return __builtin_bit_cast(float, u);
}
static __device__ __forceinline__ unsigned cvtpk_bf16(float lo, float hi) {
    unsigned r;
    asm("v_cvt_pk_bf16_f32 %0, %1, %2" : "=v"(r) : "v"(lo), "v"(hi));
    return r;
}

static __device__ __forceinline__ void async_copy16(const void* g, void* l) {
    __builtin_amdgcn_global_load_lds(
        (const __attribute__((address_space(1))) void*)g,
        (__attribute__((address_space(3))) void*)l, 16, 0, 0);
}

// PV k-order permutation sigma(j): c[5]=j[4], c[4:3]=j[3:2], c[2]=j[5],
// c[1:0]=j[1:0].  With swapped QK^T (sacc = mfma(K,Q)), lane (quad,l15)
// holds P[i=l15][j=16jb+4quad+rr], and sigma maps those 16 j's exactly onto
// PV A-operand k-slots {kb*32 + quad*8 + e} -> P never touches LDS.
// adjsel stores adj as BYTES in sigma pair order; at PV time the byte value
// itself is a v_perm selector into a one-hot 0xff table (v=4 -> zero operand).

// ---------------------------------------------------------------------------
// bf16 MFMA GEMM body (device fn, dynamic LDS): epilogue(A[M,K] @ Bw[N,K])
// BM x BN tile, 4 waves 2x2, BK=32 double-buffered 1-deep prefetch.
// ---------------------------------------------------------------------------
template<int BM, int BN, int MODE>
__device__ __forceinline__ void gemm_body(
    const short* __restrict__ A, const short* __restrict__ Bw,
    const float* __restrict__ biasv, void* __restrict__ dest,
    int M, int K, int Nw, int bx, int by, short* smem)
{
    constexpr int WTM = BM / 2, WTN = BN / 2;
    constexpr int TM = WTM / 16, TN = WTN / 16;
    short* As = smem;                    // [2][BM*32]
    short* Bs = smem + 2 * BM * 32;      // [2][BN*32]

    const int t    = threadIdx.x;
    const int lane = t & 63;
    const int w    = t >> 6;
    const int quad = lane >> 4, l15 = lane & 15;
    const int wm = w >> 1, wn = w & 1;
    const int m0 = bx * BM, n0 = by * BN;

    const int srow = lane >> 2;
    const int scol = (lane & 3) * 8;

    v4f acc[TM][TN];
    #pragma unroll
    for (int i = 0; i < TM; ++i)
        #pragma unroll
        for (int j = 0; j < TN; ++j) acc[i][j] = (v4f){0.f, 0.f, 0.f, 0.f};

    const int NK = K >> 5;

    auto stage = [&](int buf, int kt) {
        #pragma unroll
        for (int u = 0; u < BM / 64; ++u) {
            const int e0 = (w * (BM / 64) + u) * 512;
            const int row = (e0 >> 5) + srow;
            async_copy16(A + (size_t)(m0 + row) * K + kt + scol,
                         &As[buf * BM * 32 + e0]);
        }
        #pragma unroll
        for (int u = 0; u < BN / 64; ++u) {
            const int e0 = (w * (BN / 64) + u) * 512;
            const int row = (e0 >> 5) + srow;
            async_copy16(Bw + (size_t)(n0 + row) * K + kt + scol,
                         &Bs[buf * BN * 32 + e0]);
        }
    };

    stage(0, 0);

    for (int it = 0; it < NK; ++it) {
        __syncthreads();
        if (it + 1 < NK) stage((it + 1) & 1, (it + 1) << 5);

        const int buf = it & 1;
        v8s af[TM], bfr[TN];
        #pragma unroll
        for (int i = 0; i < TM; ++i)
            af[i] = *(const v8s*)&As[buf * BM * 32 +
                                     (wm * WTM + i * 16 + l15) * 32 + quad * 8];
        #pragma unroll
        for (int j = 0; j < TN; ++j)
            bfr[j] = *(const v8s*)&Bs[buf * BN * 32 +
                                      (wn * WTN + j * 16 + l15) * 32 + quad * 8];
        #pragma unroll
        for (int i = 0; i < TM; ++i)
            #pragma unroll
            for (int j = 0; j < TN; ++j)
                acc[i][j] = __builtin_amdgcn_mfma_f32_16x16x32_bf16(
                    af[i], bfr[j], acc[i][j], 0, 0, 0);
    }

    #pragma unroll
    for (int i = 0; i < TM; ++i) {
        #pragma unroll
        for (int j = 0; j < TN; ++j) {
            const int mb = m0 + wm * WTM + i * 16 + quad * 4;   // row of rr=0
            const int n  = n0 + wn * WTN + j * 16 + l15;
            float vals[4];
            if (MODE == MODE_VT) {
                #pragma unroll
                for (int rr = 0; rr < 4; ++rr) vals[rr] = acc[i][j][rr] + biasv[mb + rr];
            } else {
                #pragma unroll
                for (int rr = 0; rr < 4; ++rr) vals[rr] = acc[i][j][rr] + biasv[n];
            }

            if (MODE == MODE_QK) {
                // fold softmax scale into Q (q-plane blocks have n0 < 256)
                if (n0 < 256) {
                    #pragma unroll
                    for (int rr = 0; rr < 4; ++rr) vals[rr] *= CS;
                }
                const int b = mb >> 10, ii0 = mb & 1023;
                const int plane = n >> 8, nn = n & 255;
                const int h = nn >> 5, d = nn & 31;
                #pragma unroll
                for (int rr = 0; rr < 4; ++rr)
                    ((short*)dest)[(size_t)plane * SZH +
                        (((size_t)(b * CH + h)) * CN + ii0 + rr) * CDH + d] =
                        f2bf(vals[rr]);
            } else if (MODE == MODE_VT) {
                // sigma column permutation within each 64-token tile (see top)
                const int b = n >> 10, ii = n & 1023;
                const int jj = ii & 63;
                const int cc = (((jj >> 4) & 1) << 5) | (((jj >> 2) & 3) << 3) |
                               (((jj >> 5) & 1) << 2) | (jj & 3);
                const int iip = (ii & ~63) | cc;
                #pragma unroll
                for (int rr = 0; rr < 4; ++rr) {
                    const int m = mb + rr;
                    const int r2 = m >> 8, hd = m & 255;
                    const int h = hd >> 5, d = hd & 31;
                    ((short*)dest)[2 * SZH +
                        (((size_t)(r2 * 64 + b * CH + h)) * CDH + d) * CN + iip] =
                        f2bf(vals[rr]);
                }
            } else { // MODE_FFN1: tanh-gelu -> bf16 (x*E/(E+1))
                #pragma unroll
                for (int rr = 0; rr < 4; ++rr) {
                    const size_t idx = (size_t)(mb + rr) * Nw + n;
                    const float xx = vals[rr];
                    const float E = exp2f(2.302217f * (xx + 0.044715f * xx * xx * xx));
                    ((short*)dest)[idx] = f2bf(xx * E / (E + 1.f));
                }
            }
        }
    }
}

template<int BM, int BN, int MODE>
__global__ __launch_bounds__(256)
void gemm_mfma(const short* __restrict__ A, const short* __restrict__ Bw,
               const float* __restrict__ biasv, void* __restrict__ dest,
               int M, int K, int Nw)
{
    extern __shared__ short smem[];
    gemm_body<BM, BN, MODE>(A, Bw, biasv, dest, M, K, Nw,
                            blockIdx.x, blockIdx.y, smem);
}

// ---------------------------------------------------------------------------
// Fused projection dispatch (128x128 m97-style tiles):
//   blocks 0..255   = QK  (8192x512, K=256)
//   blocks 256..767 = V^T (1024x8192, K=256)
//   blocks 768..1279= adj int32 -> BYTE-pair pack in sigma order (adjsel)
// ---------------------------------------------------------------------------
__global__ __launch_bounds__(256)
void proj_kernel(const short* __restrict__ src_bf, const short* __restrict__ wqkvT,
                 const float* __restrict__ bpack, short* __restrict__ qkv,
                 const int* __restrict__ adj, unsigned char* __restrict__ adjsel)
{
    extern __shared__ short smem[];
    const int g = blockIdx.x;
    if (g < 256) {
        gemm_body<128, 128, MODE_QK>(src_bf, wqkvT, bpack, qkv,
                                     8192, 256, 512, g >> 2, g & 3, smem);
    } else if (g < 768) {
        const int h2 = g - 256;
        gemm_body<128, 128, MODE_VT>(wqkvT + 512 * 256, src_bf, bpack + 512,
                                     qkv, 1024, 256, 8192, h2 & 7, h2 >> 3, smem);
    } else {
        // sigma-order byte pack: int2 (row, dwi) holds adj bytes for the 8 j's
        // j0+{0..3}, j0+32+{0..3} with j0 = T*64 + (kq&3)*4 + (kq>>2)*16,
        // T = dwi>>3, kq = dwi&7  (kq = kb*4 + quad).
        const int nout = CB * CN * CN / 8;           // 1M int2 (8 j's each)
        for (int i = (g - 768) * 256 + threadIdx.x; i < nout; i += 512 * 256) {
            const int dwi = i & 127;
            const int row = i >> 7;
            const int T   = dwi >> 3, kq = dwi & 7;
            const int j0  = T * 64 + (kq & 3) * 4 + (kq >> 2) * 16;
            const int* p = adj + (size_t)row * CN + j0;
            const int4 q0 = *(const int4*)(p);
            const int4 q1 = *(const int4*)(p + 32);
            int2 o;
            o.x = (q0.x & 0xff) | ((q0.y & 0xff) << 8) |
                  ((q0.z & 0xff) << 16) | ((q0.w & 0xff) << 24);
            o.y = (q1.x & 0xff) | ((q1.y & 0xff) << 8) |
                  ((q1.z & 0xff) << 16) | ((q1.w & 0xff) << 24);
            ((int2*)adjsel)[i] = o;
        }
    }
}

// ---------------------------------------------------------------------------
// FUSED GEMM + bias + residual + LayerNorm, BM=16, BK=64 (half the barriers
// of BK=32; 8 MFMA per wave between barriers).  Granule-XOR swizzle on the
// 128B-stride LDS rows (source-side, linear dest) -> conflict-light reads.
// OUTF: write fp32 result; OUTB: write bf16 result; ADDBF: residual is bf16.
// ---------------------------------------------------------------------------
template<bool OUTF, bool OUTB, bool ADDBF>
__global__ __launch_bounds__(256)
void gemm_ln32(const short* __restrict__ A, const short* __restrict__ Bw,
               const float* __restrict__ biasv, const void* __restrict__ addp,
               const float* __restrict__ gw, const float* __restrict__ be,
               float* __restrict__ outf, short* __restrict__ outb, int K)
{
    __shared__ short As[2][16 * 64];
    __shared__ short Bs[2][256 * 64];
    __shared__ float redS[16][4], redQ[16][4];

    const int t    = threadIdx.x;
    const int lane = t & 63;
    const int w    = t >> 6;          // wave -> column quarter (64 cols)
    const int quad = lane >> 4, l15 = lane & 15;
    const int m0   = blockIdx.x * 16;
    const int xsw  = l15 & 7;         // read-side granule XOR

    v4f acc[4];
    #pragma unroll
    for (int j = 0; j < 4; ++j) acc[j] = (v4f){0.f, 0.f, 0.f, 0.f};

    const int NK = K >> 6;

    auto stage = [&](int buf, int kt) {
        if (t < 128) {   // A: 16 rows x 64 cols = 128 granules
            const int row = t >> 3, gc = t & 7;
            async_copy16(A + (size_t)(m0 + row) * K + kt + ((gc ^ (row & 7)) * 8),
                         &As[buf][t * 8]);
        }
        #pragma unroll
        for (int u = 0; u < 8; ++u) {   // B: 256 rows x 64 cols = 2048 granules
            const int gl = t + 256 * u;
            const int row = gl >> 3, gc = gl & 7;
            async_copy16(Bw + (size_t)row * K + kt + ((gc ^ (row & 7)) * 8),
                         &Bs[buf][gl * 8]);
        }
    };

    stage(0, 0);

    for (int it = 0; it < NK; ++it) {
        __syncthreads();
        if (it + 1 < NK) stage((it + 1) & 1, (it + 1) << 6);

        const int buf = it & 1;
        #pragma unroll
        for (int half = 0; half < 2; ++half) {
            const int gr = (quad + 4 * half) ^ xsw;
            const v8s af = *(const v8s*)&As[buf][l15 * 64 + gr * 8];
            #pragma unroll
            for (int j = 0; j < 4; ++j) {
                const v8s bfr = *(const v8s*)&Bs[buf][(w * 64 + 16 * j + l15) * 64 + gr * 8];
                acc[j] = __builtin_amdgcn_mfma_f32_16x16x32_bf16(af, bfr, acc[j], 0, 0, 0);
            }
        }
    }

    float v[4][4];
    #pragma unroll
    for (int rr = 0; rr < 4; ++rr) {
        const int row = m0 + quad * 4 + rr;
        float s = 0.f, sq = 0.f;
        #pragma unroll
        for (int j = 0; j < 4; ++j) {
            const int n = w * 64 + 16 * j + l15;
            const size_t idx = (size_t)row * CD + n;
            const float addv = ADDBF ? bf2f(((const short*)addp)[idx])
                                     : ((const float*)addp)[idx];
            const float x = acc[j][rr] + biasv[n] + addv;
            v[rr][j] = x;
            s += x; sq += x * x;
        }
        #pragma unroll
        for (int off = 1; off < 16; off <<= 1) {
            s  += __shfl_xor(s, off);
            sq += __shfl_xor(sq, off);
        }
        if (l15 == 0) {
            redS[quad * 4 + rr][w] = s;
            redQ[quad * 4 + rr][w] = sq;
        }
    }
    __syncthreads();

    #pragma unroll
    for (int rr = 0; rr < 4; ++rr) {
        const int r16 = quad * 4 + rr;
        const int row = m0 + r16;
        const float s  = (redS[r16][0] + redS[r16][1]) + (redS[r16][2] + redS[r16][3]);
        const float sq = (redQ[r16][0] + redQ[r16][1]) + (redQ[r16][2] + redQ[r16][3]);
        const float mean = s * (1.f / CD);
        const float var  = sq * (1.f / CD) - mean * mean;
        const float rstd = rsqrtf(var + CEPS);
        #pragma unroll
        for (int j = 0; j < 4; ++j) {
            const int n = w * 64 + 16 * j + l15;
            const float y = (v[rr][j] - mean) * rstd * gw[n] + be[n];
            if (OUTF) outf[(size_t)row * CD + n] = y;
            if (OUTB) outb[(size_t)row * CD + n] = f2bf(y);
        }
    }
}

// ---------------------------------------------------------------------------
// Prep: src->bf16, weight transposes via 64x64 LDS tiles, biases packed.
// ---------------------------------------------------------------------------
__global__ __launch_bounds__(256)
void prep(const float* __restrict__ src,
          const float* __restrict__ Wq, const float* __restrict__ Wk,
          const float* __restrict__ Wv, const float* __restrict__ Wo,
          const float* __restrict__ W1, const float* __restrict__ W2,
          const float* __restrict__ bq, const float* __restrict__ bk,
          const float* __restrict__ bv, const float* __restrict__ bo,
          const float* __restrict__ b1, const float* __restrict__ b2,
          short* __restrict__ src_bf,
          short* __restrict__ wqkvT, short* __restrict__ woT,
          short* __restrict__ w1T, short* __restrict__ w2T,
          float* __restrict__ bpack)
{
    __shared__ float tile[64][65];
    const int bx = blockIdx.x, t = threadIdx.x;
    if (bx < 2048) {                                   // src cast: 512K float4
        const int i = bx * 256 + t;
        const float4 v = ((const float4*)src)[i];
        short4 o;
        o.x = f2bf(v.x); o.y = f2bf(v.y); o.z = f2bf(v.z); o.w = f2bf(v.w);
        ((short4*)src_bf)[i] = o;
    } else if (bx < 2288) {                            // weight transposes
        const int tt = bx - 2048;
        const float* S; short* D;
        int Sstride, Dstride, k0, srccol, dstrow;
        if (tt < 96) {                                 // wqkv: 24x4 tiles
            const int tk = tt & 3, tn = tt >> 2;
            const int ng = tn * 64;
            Sstride = 256; Dstride = 256; k0 = tk * 64;
            dstrow = tn * 64; D = wqkvT;
            if (ng < 256)      { S = Wq; srccol = ng; }
            else if (ng < 512) { S = Wk; srccol = ng - 256; }
            else { const int r = (ng - 512) >> 8;
                   S = Wv + (size_t)r * 65536; srccol = (ng - 512) & 255; }
        } else if (tt < 112) {                         // wo: 4x4
            const int u = tt - 96, tk = u & 3, tn = u >> 2;
            S = Wo; Sstride = 256; D = woT; Dstride = 256;
            k0 = tk * 64; srccol = tn * 64; dstrow = tn * 64;
        } else if (tt < 176) {                         // w1: 16x4
            const int u = tt - 112, tk = u & 3, tn = u >> 2;
            S = W1; Sstride = 1024; D = w1T; Dstride = 256;
            k0 = tk * 64; srccol = tn * 64; dstrow = tn * 64;
        } else {                                       // w2: 4x16
            const int u = tt - 176, tk = u & 15, tn = u >> 4;
            S = W2; Sstride = 256; D = w2T; Dstride = 1024;
            k0 = tk * 64; srccol = tn * 64; dstrow = tn * 64;
        }
        #pragma unroll
        for (int u2 = 0; u2 < 4; ++u2) {               // coalesced read
            const int kl = (t >> 4) + u2 * 16;
            const int nl = (t & 15) * 4;
            const float4 v = *(const float4*)&S[(size_t)(k0 + kl) * Sstride + srccol + nl];
            tile[kl][nl + 0] = v.x; tile[kl][nl + 1] = v.y;
            tile[kl][nl + 2] = v.z; tile[kl][nl + 3] = v.w;
        }
        __syncthreads();
        #pragma unroll
        for (int u2 = 0; u2 < 4; ++u2) {               // coalesced write
            const int nl = (t >> 4) + u2 * 16;
            const int kl = (t & 15) * 4;
            short4 o;
            o.x = f2bf(tile[kl + 0][nl]); o.y = f2bf(tile[kl + 1][nl]);
            o.z = f2bf(tile[kl + 2][nl]); o.w = f2bf(tile[kl + 3][nl]);
            *(short4*)&D[(size_t)(dstrow + nl) * Dstride + k0 + kl] = o;
        }
    } else {                                           // biases: 3072
        const int idx = (bx - 2288) * 256 + t;
        float bvv;
        if (idx < 256)       bvv = bq[idx];
        else if (idx < 512)  bvv = bk[idx - 256];
        else if (idx < 1536) bvv = bv[idx - 512];
        else if (idx < 1792) bvv = bo[idx - 1536];
        else if (idx < 2816) bvv = b1[idx - 1792];
        else                 bvv = b2[idx - 2816];
        bpack[idx] = bvv;
    }
}

// ---------------------------------------------------------------------------
// Fused relational attention, 128 Q-rows per block (2 independent halves):
//  - each wave carries TWO dependency chains (hh=0,1) that interleave and
//    self-hide latency; K frags and V frags loaded ONCE, reused by both
//  - QK^T swapped (sacc = mfma(K,Q)) -> P lane-local; sigma k-order feeds PV
//  - byte-LUT masks via v_perm with adj byte as selector
//  - V^T staged by global_load_lds 2-deep ring; K/adjsel direct from L2
// One __syncthreads per j-tile.  XCD-aware 1D grid, 512 blocks (b = g & 7).
// ---------------------------------------------------------------------------
__global__ __launch_bounds__(256, 2)
void attn_mfma(const short* __restrict__ qg, const short* __restrict__ kg,
               const short* __restrict__ vt, const unsigned char* __restrict__ adjsel,
               short* __restrict__ outh)
{
    __shared__ __align__(16) short vtl[2][8192];  // [buf][r*2048 + d*64 + gc*8]

    const int t    = threadIdx.x;
    const int lane = t & 63;
    const int w    = t >> 6;          // wave 0..3
    const int quad = lane >> 4;
    const int l15  = lane & 15;
    const int g    = blockIdx.x;      // 1D grid, XCD-aware decode
    const int b    = g & 7;           // same XCD for whole batch
    const int h    = (g >> 3) & 7;
    const int i0   = (g >> 6) * 128;  // 8 tiles of 128 rows
    const int bhh  = b * CH + h;
    const size_t bh = (size_t)bhh;

    v8s qfrag[2];
    #pragma unroll
    for (int hh = 0; hh < 2; ++hh)
        qfrag[hh] = *(const v8s*)&qg[(bh * CN + i0 + 64 * hh + 16 * w + l15) * CDH + quad * 8];

    // V DMA sources: thread t stages granule gl = t + 256u; LDS granule
    // (r,d,gc) holds global granule gc^(d&7) of V^T row (r,d) in this j-tile.
    const short* vsrc[4];
    #pragma unroll
    for (int u = 0; u < 4; ++u) {
        const int gl = t + 256 * u;
        const int r = gl >> 8, d = (gl >> 3) & 31, gc = gl & 7;
        vsrc[u] = vt + ((size_t)(r * 64 + bhh) * CDH + d) * CN + (gc ^ (d & 7)) * 8;
    }
    // K direct: A-operand rows l15, k-chunk quad*8
    const short* kbase = kg + (bh * CN + l15) * CDH + quad * 8;
    // adjsel direct: row i0+64*hh+16w+l15, int2 (kb, quad) of the 64B slice
    const unsigned char* abase[2];
    #pragma unroll
    for (int hh = 0; hh < 2; ++hh)
        abase[hh] = adjsel + ((size_t)(b * CN) + i0 + 64 * hh + 16 * w + l15) * CN + quad * 8;

    v4f oacc[2][2][2];                 // [hh][cb][kb]
    #pragma unroll
    for (int hh = 0; hh < 2; ++hh)
        #pragma unroll
        for (int cb = 0; cb < 2; ++cb)
            #pragma unroll
            for (int kb = 0; kb < 2; ++kb) oacc[hh][cb][kb] = (v4f){0.f, 0.f, 0.f, 0.f};
    float plsum[2] = {0.f, 0.f};
    const int psw = (l15 & 7) * 8;         // vfrag granule XOR (pre-scaled)

    // ---- prologue: prefetch tile 0 ----
    #pragma unroll
    for (int u = 0; u < 4; ++u)
        async_copy16(vsrc[u], &vtl[0][(t + 256 * u) * 8]);
    v8s kpre[4];
    #pragma unroll
    for (int jb = 0; jb < 4; ++jb)
        kpre[jb] = *(const v8s*)(kbase + (16 * jb) * CDH);
    int2 apre[2][2];
    #pragma unroll
    for (int hh = 0; hh < 2; ++hh) {
        apre[hh][0] = *(const int2*)(abase[hh]);
        apre[hh][1] = *(const int2*)(abase[hh] + 32);
    }

    for (int jt = 0; jt < 16; ++jt) {
        __syncthreads();   // vtl[jt&1] staged; other buf free for prefetch
        const int p = jt & 1;

        // ---- QK swapped, both halves share kpre ----
        v4f sacc[2][4];
        #pragma unroll
        for (int hh = 0; hh < 2; ++hh)
            #pragma unroll
            for (int jb = 0; jb < 4; ++jb)
                sacc[hh][jb] = __builtin_amdgcn_mfma_f32_16x16x32_bf16(
                    kpre[jb], qfrag[hh], (v4f){0.f, 0.f, 0.f, 0.f}, 0, 0, 0);

        // ---- issue prefetches for tile jt+1 (wrap harmless on last iter) ----
        int2 aa[2][2];
        #pragma unroll
        for (int hh = 0; hh < 2; ++hh) {
            aa[hh][0] = apre[hh][0];
            aa[hh][1] = apre[hh][1];
        }
        const int jn = (jt + 1) & 15;
        #pragma unroll
        for (int u = 0; u < 4; ++u)
            async_copy16(vsrc[u] + jn * 64, &vtl[p ^ 1][(t + 256 * u) * 8]);
        #pragma unroll
        for (int jb = 0; jb < 4; ++jb)
            kpre[jb] = *(const v8s*)(kbase + (jn * 64 + 16 * jb) * CDH);
        #pragma unroll
        for (int hh = 0; hh < 2; ++hh) {
            apre[hh][0] = *(const int2*)(abase[hh] + jn * 64);
            apre[hh][1] = *(const int2*)(abase[hh] + jn * 64 + 32);
        }

        // ---- softmax numerators, both halves, all in registers ----
        float pv[2][4][4];   // [hh][jb][rr] = P[i=l15][j=16jb+4quad+rr]
        #pragma unroll
        for (int hh = 0; hh < 2; ++hh) {
            #pragma unroll
            for (int jb = 0; jb < 4; ++jb)
                #pragma unroll
                for (int rr = 0; rr < 4; ++rr) pv[hh][jb][rr] = exp2f(sacc[hh][jb][rr]);
            plsum[hh] += ((pv[hh][0][0] + pv[hh][0][1]) + (pv[hh][0][2] + pv[hh][0][3]))
                       + ((pv[hh][1][0] + pv[hh][1][1]) + (pv[hh][1][2] + pv[hh][1][3]))
                       + ((pv[hh][2][0] + pv[hh][2][1]) + (pv[hh][2][2] + pv[hh][2][3]))
                       + ((pv[hh][3][0] + pv[hh][3][1]) + (pv[hh][3][2] + pv[hh][3][3]));
        }

        // ---- PV: vf loaded once per kb, reused by both halves ----
        #pragma unroll
        for (int kb = 0; kb < 2; ++kb) {
            v8s vf[4][2];
            #pragma unroll
            for (int r = 0; r < 4; ++r)
                #pragma unroll
                for (int cb = 0; cb < 2; ++cb)
                    vf[r][cb] = *(const v8s*)&vtl[p][r * 2048 +
                        (16 * cb + l15) * 64 + (((4 * kb + quad) * 8) ^ psw)];

            #pragma unroll
            for (int hh = 0; hh < 2; ++hh) {
                // A-operand dwords: e = {0..7} = rr of jb=kb then rr of jb=kb+2
                const unsigned P[4] = {
                    cvtpk_bf16(pv[hh][kb][0],     pv[hh][kb][1]),
                    cvtpk_bf16(pv[hh][kb][2],     pv[hh][kb][3]),
                    cvtpk_bf16(pv[hh][kb + 2][0], pv[hh][kb + 2][1]),
                    cvtpk_bf16(pv[hh][kb + 2][2], pv[hh][kb + 2][3])};
                const int2 a2 = aa[hh][kb];
                // D[u] = [v0,v0,v1,v1] bytes for pair u
                const unsigned D[4] = {
                    __builtin_amdgcn_perm((unsigned)a2.x, (unsigned)a2.x, 0x01010000u),
                    __builtin_amdgcn_perm((unsigned)a2.x, (unsigned)a2.x, 0x03030202u),
                    __builtin_amdgcn_perm((unsigned)a2.y, (unsigned)a2.y, 0x01010000u),
                    __builtin_amdgcn_perm((unsigned)a2.y, (unsigned)a2.y, 0x03030202u)};
                unsigned pfm[4][4];
                #pragma unroll
                for (int r = 0; r < 4; ++r) {
                    const unsigned tb = 0xffu << (8 * r);   // one-hot byte table
                    #pragma unroll
                    for (int u = 0; u < 4; ++u)
                        pfm[r][u] = P[u] & __builtin_amdgcn_perm(0u, tb, D[u]);
                }
                __builtin_amdgcn_s_setprio(1);
                #pragma unroll
                for (int r = 0; r < 4; ++r) {
                    const v8s pfr = __builtin_bit_cast(v8s,
                        make_uint4(pfm[r][0], pfm[r][1], pfm[r][2], pfm[r][3]));
                    #pragma unroll
                    for (int cb = 0; cb < 2; ++cb)
                        oacc[hh][cb][kb] = __builtin_amdgcn_mfma_f32_16x16x32_bf16(
                            pfr, vf[r][cb], oacc[hh][cb][kb], 0, 0, 0);
                }
                __builtin_amdgcn_s_setprio(0);
            }
        }
    }

    // ---- epilogue: merge split accumulators, reduce plsum, normalize ----
    #pragma unroll
    for (int hh = 0; hh < 2; ++hh) {
        v4f ofin[2];
        ofin[0] = oacc[hh][0][0] + oacc[hh][0][1];
        ofin[1] = oacc[hh][1][0] + oacc[hh][1][1];
        float plF = plsum[hh];
        plF += __shfl_xor(plF, 16);
        plF += __shfl_xor(plF, 32);        // lane x: denom for row i=x&15
        #pragma unroll
        for (int rr = 0; rr < 4; ++rr) {
            const float inv = 1.f / __shfl(plF, quad * 4 + rr);
            const int row = i0 + 64 * hh + 16 * w + quad * 4 + rr;
            #pragma unroll
            for (int cb = 0; cb < 2; ++cb)
                outh[((size_t)b * CN + row) * CD + h * CDH + 16 * cb + l15] =
                    f2bf(ofin[cb][rr] * inv);
        }
    }
}

// ---------------------------------------------------------------------------
extern "C" void kernel_launch(void* const* d_in, const int* in_sizes, int n_in,
                              void* d_out, int out_size, void* d_ws, size_t ws_size,
                              hipStream_t stream)
{
    const float* src = (const float*)d_in[0];
    const int*   adj = (const int*)d_in[1];
    const float* Wq  = (const float*)d_in[2];
    const float* bq  = (const float*)d_in[3];
    const float* Wk  = (const float*)d_in[4];
    const float* bk  = (const float*)d_in[5];
    const float* Wv  = (const float*)d_in[6];
    const float* bv  = (const float*)d_in[7];
    const float* Wo  = (const float*)d_in[8];
    const float* bo  = (const float*)d_in[9];
    const float* W1  = (const float*)d_in[10];
    const float* b1  = (const float*)d_in[11];
    const float* W2  = (const float*)d_in[12];
    const float* b2  = (const float*)d_in[13];
    const float* g1  = (const float*)d_in[14];
    const float* be1 = (const float*)d_in[15];
    const float* g2  = (const float*)d_in[16];
    const float* be2 = (const float*)d_in[17];
    float* out = (float*)d_out;

    char* wsb = (char*)d_ws;
    const size_t MB = (size_t)1 << 20;

    // workspace layout (42 MB with aliasing)
    unsigned char* adjsel = (unsigned char*)(wsb);          // [0,8) MB byte-pair adj
    short* qkv_bf = (short*)(wsb + 8 * MB);                 // [8,32): q,k planes + vT
    short* src_bf = (short*)(wsb + 32 * MB);                // [32,36)
    short* wqkvT  = (short*)(wsb + 36 * MB);                // 768 KB
    short* woT    = (short*)(wsb + 36 * MB + 768 * 1024);   // 128 KB
    short* w1T    = (short*)(wsb + 36 * MB + 896 * 1024);   // 512 KB
    short* w2T    = (short*)(wsb + 36 * MB + 1408 * 1024);  // 512 KB
    float* bpack  = (float*)(wsb + 36 * MB + 1920 * 1024);  // 12 KB
    short* heads_bf = (short*)(wsb + 38 * MB);              // [38,42)
    short* x_bf   = (short*)(wsb + 32 * MB);                // reuse src_bf (LN1 out)
    short* h1_bf  = (short*)(wsb + 16 * MB);                // reuse vT (dead post-attn)

    const int M = CB * CN;        // 8192
    dim3 blk(256);

    // prep: src cast, coalesced weight transposes, biases (2300 blocks)
    prep<<<dim3(2300), blk, 0, stream>>>(src, Wq, Wk, Wv, Wo, W1, W2,
        bq, bk, bv, bo, b1, b2, src_bf, wqkvT, woT, w1T, w2T, bpack);

    // fused QK + V^T projection (128x128 tiles) + sigma byte pack: 1280 blocks
    proj_kernel<<<dim3(1280), blk, 32768, stream>>>(
        src_bf, wqkvT, bpack, qkv_bf, adj, adjsel);

    // fused relational MFMA attention (XCD-aware 1D grid, 128 rows/block)
    attn_mfma<<<dim3(512), blk, 0, stream>>>(
        qkv_bf, qkv_bf + SZH, qkv_bf + 2 * SZH, adjsel, heads_bf);

    // O-projection + bias + residual(src fp32) + LN1 -> x_bf bf16 only
    gemm_ln32<false, true, false><<<dim3(M / 16), blk, 0, stream>>>(
        heads_bf, woT, bpack + 1536, src, g1, be1, nullptr, x_bf, CD);

    // FFN1 (128x128 tiles): 512 blocks
    gemm_mfma<128, 128, MODE_FFN1><<<dim3(M / 128, CFF / 128), blk, 32768, stream>>>(
        x_bf, w1T, bpack + 1792, h1_bf, M, CD, CFF);

    // FFN2 + bias + residual(x_bf bf16) + LN2 -> out fp32
    gemm_ln32<true, false, true><<<dim3(M / 16), blk, 0, stream>>>(
        h1_bf, w2T, bpack + 2816, x_bf, g2, be2, out, nullptr, CFF);
}